// Round 1
// baseline (972.677 us; speedup 1.0000x reference)
//
#include <hip/hip_runtime.h>

#define NEGV (-1000000000.0f)

typedef __attribute__((ext_vector_type(8))) short sh8;
typedef __attribute__((ext_vector_type(4))) short sh4;
typedef __attribute__((ext_vector_type(8))) __bf16 bf16x8;
typedef __attribute__((ext_vector_type(4))) float f32x4;

__device__ __forceinline__ float b2f(unsigned short u) {
  unsigned v = ((unsigned)u) << 16;
  return __builtin_bit_cast(float, v);
}
__device__ __forceinline__ unsigned short f2b(float f) {
  unsigned x = __builtin_bit_cast(unsigned, f);
  unsigned r = (x + 0x7fffu + ((x >> 16) & 1u)) >> 16;
  return (unsigned short)r;
}
__device__ __forceinline__ void g2l16(const void* g, void* l) {
  __builtin_amdgcn_global_load_lds((const __attribute__((address_space(1))) unsigned int*)g,
                                   (__attribute__((address_space(3))) unsigned int*)l, 16, 0, 0);
}
__device__ __forceinline__ f32x4 mfma16(bf16x8 a, bf16x8 b, f32x4 c) {
  return __builtin_amdgcn_mfma_f32_16x16x32_bf16(a, b, c, 0, 0, 0);
}
__device__ __forceinline__ float fast_tanh(float x) {
  x = fminf(fmaxf(x, -15.f), 15.f);
  float e = __expf(2.f * x);
  return (e - 1.f) / (e + 1.f);
}

// ---------------- conversion kernels ----------------
__global__ void cvt_bf16(const float* __restrict__ src, unsigned short* __restrict__ dst, int n4) {
  int i = blockIdx.x * blockDim.x + threadIdx.x;
  int stride = gridDim.x * blockDim.x;
  for (; i < n4; i += stride) {
    float4 v = ((const float4*)src)[i];
    sh4 o;
    o[0] = (short)f2b(v.x); o[1] = (short)f2b(v.y);
    o[2] = (short)f2b(v.z); o[3] = (short)f2b(v.w);
    ((sh4*)dst)[i] = o;
  }
}

// dst[n][k] = bf16(src[k][n]) for 1024x1024
__global__ void tcvt(const float* __restrict__ src, unsigned short* __restrict__ dst) {
  __shared__ float tile[64][65];
  int bx = blockIdx.x, by = blockIdx.y;
  int tx = threadIdx.x & 63, ty = threadIdx.x >> 6;
#pragma unroll
  for (int i = 0; i < 16; ++i) {
    int r = i * 4 + ty;
    tile[r][tx] = src[(size_t)(by * 64 + r) * 1024 + bx * 64 + tx];
  }
  __syncthreads();
#pragma unroll
  for (int i = 0; i < 16; ++i) {
    int r = i * 4 + ty;
    dst[(size_t)(bx * 64 + r) * 1024 + by * 64 + tx] = f2b(tile[tx][r]);
  }
}

// ---------------- 128x128 bf16 MFMA GEMM, K=N=1024 ----------------
// A: M x 1024 bf16, Bt: 1024 x 1024 bf16 (n-major: Bt[n][k])
// EPI 0: C=bf16(acc+bias) row-major; EPI 1: v-transposed write; EPI 2: tanh-dot-atomic score
template<int EPI>
__global__ __launch_bounds__(256, 2)
void gemm128(const unsigned short* __restrict__ A, const unsigned short* __restrict__ Bt,
             const float* __restrict__ bias, unsigned short* __restrict__ C,
             const float* __restrict__ aq, const float* __restrict__ wa,
             float* __restrict__ sc)
{
  __shared__ unsigned short ldsA[128 * 32];
  __shared__ unsigned short ldsB[128 * 32];
  const int tid = threadIdx.x;
  const int w = tid >> 6, l = tid & 63;
  const int wr = w >> 1, wc = w & 1;
  const int lr = l & 15, lk8 = (l >> 4) * 8;
  const int m0 = blockIdx.y * 128;
  const int n0 = blockIdx.x * 128;

  f32x4 acc[4][4] = {};

  const int srow = tid >> 2;
  const int scol = (tid & 3) * 8;
  const unsigned short* gA0 = A + (size_t)(m0 + srow) * 1024 + scol;
  const unsigned short* gB0 = Bt + (size_t)(n0 + srow) * 1024 + scol;
  unsigned short* lA = &ldsA[w * 512];
  unsigned short* lB = &ldsB[w * 512];

  for (int kt = 0; kt < 32; ++kt) {
    const int k0 = kt * 32;
    g2l16(gA0 + k0, lA);
    g2l16(gA0 + 64 * 1024 + k0, lA + 2048);
    g2l16(gB0 + k0, lB);
    g2l16(gB0 + 64 * 1024 + k0, lB + 2048);
    __syncthreads();
    bf16x8 af[4], bf[4];
#pragma unroll
    for (int i = 0; i < 4; ++i)
      af[i] = *(const bf16x8*)&ldsA[(wr * 64 + i * 16 + lr) * 32 + lk8];
#pragma unroll
    for (int j = 0; j < 4; ++j)
      bf[j] = *(const bf16x8*)&ldsB[(wc * 64 + j * 16 + lr) * 32 + lk8];
#pragma unroll
    for (int i = 0; i < 4; ++i)
#pragma unroll
      for (int j = 0; j < 4; ++j)
        acc[i][j] = mfma16(af[i], bf[j], acc[i][j]);
    __syncthreads();
  }

  if (EPI == 0) {
#pragma unroll
    for (int j = 0; j < 4; ++j) {
      int col = n0 + wc * 64 + j * 16 + lr;
      float bv = bias[col];
#pragma unroll
      for (int i = 0; i < 4; ++i) {
        int rowb = m0 + wr * 64 + i * 16 + (l >> 4) * 4;
#pragma unroll
        for (int r = 0; r < 4; ++r)
          C[(size_t)(rowb + r) * 1024 + col] = f2b(acc[i][j][r] + bv);
      }
    }
  } else if (EPI == 1) {
#pragma unroll
    for (int j = 0; j < 4; ++j) {
      int col = n0 + wc * 64 + j * 16 + lr;
      float bv = bias[col];
      int h = col >> 8, d = col & 255;
#pragma unroll
      for (int i = 0; i < 4; ++i) {
        int rowb = m0 + wr * 64 + i * 16 + (l >> 4) * 4;
        int bb = rowb >> 9, ll = rowb & 511;
        size_t base = ((size_t)(bb * 4 + h) * 256 + d) * 512 + ll;
#pragma unroll
        for (int r = 0; r < 4; ++r)
          C[base + r] = f2b(acc[i][j][r] + bv);
      }
    }
  } else {
    const int bb = m0 >> 11;
#pragma unroll
    for (int i = 0; i < 4; ++i) {
      float rp[4] = {0.f, 0.f, 0.f, 0.f};
#pragma unroll
      for (int j = 0; j < 4; ++j) {
        int col = n0 + wc * 64 + j * 16 + lr;
        float wav = wa[col];
        float aqv = aq[bb * 1024 + col];
#pragma unroll
        for (int r = 0; r < 4; ++r)
          rp[r] += wav * fast_tanh(acc[i][j][r] + aqv);
      }
#pragma unroll
      for (int off = 1; off < 16; off <<= 1)
#pragma unroll
        for (int r = 0; r < 4; ++r)
          rp[r] += __shfl_xor(rp[r], off, 64);
      if (lr == 0) {
        int rowb = m0 + wr * 64 + i * 16 + (l >> 4) * 4;
#pragma unroll
        for (int r = 0; r < 4; ++r)
          atomicAdd(&sc[rowb + r], rp[r]);
      }
    }
  }
}

// ---------------- fused attention ----------------
// LDS: Ss f32[32][516] at 0 (66048 B); Qs u16[32][264] / Ps u16[32][520] at 66048 (33280 B)
__global__ __launch_bounds__(256, 1)
void attn_kernel(const unsigned short* __restrict__ q, const unsigned short* __restrict__ k,
                 const unsigned short* __restrict__ vT, const float* __restrict__ seq_mask,
                 unsigned short* __restrict__ ctx, float* __restrict__ attn_out)
{
  extern __shared__ char smem[];
  float* Ss = (float*)smem;
  unsigned short* Qs = (unsigned short*)(smem + 66048);
  unsigned short* Ps = (unsigned short*)(smem + 66048);
  const int t = threadIdx.x, w = t >> 6, l = t & 63;
  const int lr = l & 15, lk8 = (l >> 4) * 8;
  const int qt = blockIdx.x, h = blockIdx.y, b = blockIdx.z;
  const int l0 = qt * 32;

  for (int idx = t; idx < 32 * 32; idx += 256) {
    int r = idx >> 5, ch = (idx & 31) * 8;
    *(sh8*)&Qs[r * 264 + ch] =
        *(const sh8*)&q[((size_t)(b * 512 + l0 + r)) * 1024 + h * 256 + ch];
  }
  __syncthreads();

  // QK^T : wave w handles kj in [w*128, w*128+128)
  f32x4 accs[2][8] = {};
  const unsigned short* kbase = k + ((size_t)b * 512) * 1024 + h * 256;
#pragma unroll
  for (int ds = 0; ds < 8; ++ds) {
    int d0 = ds * 32;
    bf16x8 a0 = *(const bf16x8*)&Qs[lr * 264 + d0 + lk8];
    bf16x8 a1 = *(const bf16x8*)&Qs[(16 + lr) * 264 + d0 + lk8];
#pragma unroll
    for (int j = 0; j < 8; ++j) {
      int kj = w * 128 + j * 16 + lr;
      bf16x8 bb = *(const bf16x8*)&kbase[(size_t)kj * 1024 + d0 + lk8];
      accs[0][j] = mfma16(a0, bb, accs[0][j]);
      accs[1][j] = mfma16(a1, bb, accs[1][j]);
    }
  }
#pragma unroll
  for (int j = 0; j < 8; ++j) {
    int col = w * 128 + j * 16 + lr;
    float mv = seq_mask[b * 512 + col];
    bool msk = (mv == 0.f);
#pragma unroll
    for (int i = 0; i < 2; ++i) {
      int rowb = i * 16 + (l >> 4) * 4;
#pragma unroll
      for (int r = 0; r < 4; ++r) {
        float sv = accs[i][j][r] * 0.0625f;
        Ss[(rowb + r) * 516 + col] = msk ? NEGV : sv;
      }
    }
  }
  __syncthreads();

  // softmax: wave w owns rows w*8..w*8+7; 8 lanes per row
  const int srow = w * 8 + (l >> 3);
  const int c0 = l & 7;
  float mx = -3.0e38f;
  for (int i = 0; i < 64; ++i) mx = fmaxf(mx, Ss[srow * 516 + c0 + 8 * i]);
#pragma unroll
  for (int off = 1; off < 8; off <<= 1) mx = fmaxf(mx, __shfl_xor(mx, off, 64));
  float sum = 0.f;
  for (int i = 0; i < 64; ++i) {
    float p = __expf(Ss[srow * 516 + c0 + 8 * i] - mx);
    Ss[srow * 516 + c0 + 8 * i] = p;
    sum += p;
  }
#pragma unroll
  for (int off = 1; off < 8; off <<= 1) sum += __shfl_xor(sum, off, 64);
  float inv = 1.f / sum;
  for (int i = 0; i < 64; ++i) {
    int cc = c0 + 8 * i;
    float pn = Ss[srow * 516 + cc] * inv;
    Ss[srow * 516 + cc] = pn;
    Ps[srow * 520 + cc] = f2b(pn);
  }
  __syncthreads();

  if (h == 0) {
    for (int idx = t; idx < 32 * 512; idx += 256) {
      int r = idx >> 9, cc = idx & 511;
      attn_out[((size_t)b * 512 + l0 + r) * 512 + cc] = Ss[r * 516 + cc];
    }
  }

  // PV : wave w handles d in [w*64, w*64+64)
  f32x4 acco[2][4] = {};
  const unsigned short* vbase = vT + ((size_t)(b * 4 + h)) * 256 * 512;
#pragma unroll
  for (int ks = 0; ks < 16; ++ks) {
    int kj0 = ks * 32;
    bf16x8 a0 = *(const bf16x8*)&Ps[lr * 520 + kj0 + lk8];
    bf16x8 a1 = *(const bf16x8*)&Ps[(16 + lr) * 520 + kj0 + lk8];
#pragma unroll
    for (int j = 0; j < 4; ++j) {
      int d = w * 64 + j * 16 + lr;
      bf16x8 bb = *(const bf16x8*)&vbase[(size_t)d * 512 + kj0 + lk8];
      acco[0][j] = mfma16(a0, bb, acco[0][j]);
      acco[1][j] = mfma16(a1, bb, acco[1][j]);
    }
  }
#pragma unroll
  for (int i = 0; i < 2; ++i)
#pragma unroll
    for (int j = 0; j < 4; ++j) {
      int col = w * 64 + j * 16 + lr;
#pragma unroll
      for (int r = 0; r < 4; ++r) {
        int row = i * 16 + (l >> 4) * 4 + r;
        ctx[((size_t)(b * 512 + l0 + row)) * 1024 + h * 256 + col] = f2b(acco[i][j][r]);
      }
    }
}

// ---------------- LN + masked mean over L ----------------
__global__ __launch_bounds__(256)
void ln_mean(const unsigned short* __restrict__ sa, const float* __restrict__ g,
             const float* __restrict__ bt, const float* __restrict__ mask,
             float* __restrict__ poi_sum)
{
  const int b = blockIdx.y, ch = blockIdx.x;
  const int t = threadIdx.x, w = t >> 6, l = t & 63;
  float gg[16], bb[16];
#pragma unroll
  for (int j = 0; j < 16; ++j) { gg[j] = g[l * 16 + j]; bb[j] = bt[l * 16 + j]; }
  float accv[16];
#pragma unroll
  for (int j = 0; j < 16; ++j) accv[j] = 0.f;
  for (int rr = 0; rr < 16; ++rr) {
    int row = ch * 64 + w * 16 + rr;
    const unsigned short* rp = sa + ((size_t)(b * 512 + row)) * 1024 + l * 16;
    float x[16];
    sh8 v0 = *(const sh8*)rp;
    sh8 v1 = *(const sh8*)(rp + 8);
#pragma unroll
    for (int j = 0; j < 8; ++j) {
      x[j] = b2f((unsigned short)v0[j]);
      x[8 + j] = b2f((unsigned short)v1[j]);
    }
    float s = 0.f, s2 = 0.f;
#pragma unroll
    for (int j = 0; j < 16; ++j) { s += x[j]; s2 += x[j] * x[j]; }
#pragma unroll
    for (int off = 1; off < 64; off <<= 1) {
      s += __shfl_xor(s, off, 64);
      s2 += __shfl_xor(s2, off, 64);
    }
    float mean = s * (1.f / 1024.f);
    float var = s2 * (1.f / 1024.f) - mean * mean;
    float rinv = rsqrtf(var + 1e-5f);
    float mk = mask[b * 512 + row];
#pragma unroll
    for (int j = 0; j < 16; ++j) accv[j] += ((x[j] - mean) * rinv * gg[j] + bb[j]) * mk;
  }
#pragma unroll
  for (int j = 0; j < 16; ++j) atomicAdd(&poi_sum[b * 1024 + l * 16 + j], accv[j]);
}

__global__ void finalize_poi(const float* __restrict__ ps, float* __restrict__ poi) {
  int i = blockIdx.x * 256 + threadIdx.x;
  if (i < 32 * 1024) poi[i] = ps[i] * (1.f / 512.f);
}

// out[b][n] = sum_d in[b][d] * W[d][n]
__global__ __launch_bounds__(256)
void gemv32(const float* __restrict__ in, const float* __restrict__ W, float* __restrict__ out)
{
  const int b = blockIdx.y;
  const int n = blockIdx.x * 256 + threadIdx.x;
  const float* ib = in + b * 1024;
  float acc = 0.f;
  for (int d = 0; d < 1024; d += 4) {
    acc += ib[d]     * W[(size_t)d * 1024 + n]
         + ib[d + 1] * W[(size_t)(d + 1) * 1024 + n]
         + ib[d + 2] * W[(size_t)(d + 2) * 1024 + n]
         + ib[d + 3] * W[(size_t)(d + 3) * 1024 + n];
  }
  out[b * 1024 + n] = acc;
}

__global__ __launch_bounds__(256)
void softmax_his(float* __restrict__ sc, const float* __restrict__ mask)
{
  __shared__ float red[4];
  const int b = blockIdx.x, t = threadIdx.x, w = t >> 6, l = t & 63;
  float v[8];
  float mx = -3.0e38f;
#pragma unroll
  for (int i = 0; i < 8; ++i) {
    int kk = t + i * 256;
    float s = (mask[b * 2048 + kk] == 0.f) ? NEGV : sc[b * 2048 + kk];
    v[i] = s;
    mx = fmaxf(mx, s);
  }
#pragma unroll
  for (int off = 1; off < 64; off <<= 1) mx = fmaxf(mx, __shfl_xor(mx, off, 64));
  if (l == 0) red[w] = mx;
  __syncthreads();
  mx = fmaxf(fmaxf(red[0], red[1]), fmaxf(red[2], red[3]));
  float sum = 0.f;
#pragma unroll
  for (int i = 0; i < 8; ++i) { v[i] = __expf(v[i] - mx); sum += v[i]; }
#pragma unroll
  for (int off = 1; off < 64; off <<= 1) sum += __shfl_xor(sum, off, 64);
  __syncthreads();
  if (l == 0) red[w] = sum;
  __syncthreads();
  sum = red[0] + red[1] + red[2] + red[3];
  float inv = 1.f / sum;
#pragma unroll
  for (int i = 0; i < 8; ++i) sc[b * 2048 + t + i * 256] = v[i] * inv;
}

// hw[b][d] = sum_k aw[b][k] * his_bf16[b][k][d]
__global__ __launch_bounds__(256)
void hw_kernel(const float* __restrict__ aw, const unsigned short* __restrict__ his,
               float* __restrict__ hw)
{
  const int b = blockIdx.y, kc = blockIdx.x, t = threadIdx.x;
  const int cb = t * 4;
  float a0 = 0.f, a1 = 0.f, a2 = 0.f, a3 = 0.f;
  for (int kk = 0; kk < 256; ++kk) {
    int k = kc * 256 + kk;
    float wg = aw[b * 2048 + k];
    sh4 vv = *(const sh4*)&his[((size_t)(b * 2048 + k)) * 1024 + cb];
    a0 += wg * b2f((unsigned short)vv[0]);
    a1 += wg * b2f((unsigned short)vv[1]);
    a2 += wg * b2f((unsigned short)vv[2]);
    a3 += wg * b2f((unsigned short)vv[3]);
  }
  atomicAdd(&hw[b * 1024 + cb + 0], a0);
  atomicAdd(&hw[b * 1024 + cb + 1], a1);
  atomicAdd(&hw[b * 1024 + cb + 2], a2);
  atomicAdd(&hw[b * 1024 + cb + 3], a3);
}

__global__ __launch_bounds__(256)
void final_kernel(const float* __restrict__ aa_out, const float* __restrict__ g,
                  const float* __restrict__ bt, const float* __restrict__ poi,
                  float* __restrict__ out)
{
  __shared__ float r1[4], r2[4];
  const int b = blockIdx.x, t = threadIdx.x, w = t >> 6, l = t & 63;
  float x[4];
#pragma unroll
  for (int j = 0; j < 4; ++j) x[j] = aa_out[b * 1024 + t * 4 + j];
  float s = 0.f, s2 = 0.f;
#pragma unroll
  for (int j = 0; j < 4; ++j) { s += x[j]; s2 += x[j] * x[j]; }
#pragma unroll
  for (int off = 1; off < 64; off <<= 1) {
    s += __shfl_xor(s, off, 64);
    s2 += __shfl_xor(s2, off, 64);
  }
  if (l == 0) { r1[w] = s; r2[w] = s2; }
  __syncthreads();
  s = r1[0] + r1[1] + r1[2] + r1[3];
  s2 = r2[0] + r2[1] + r2[2] + r2[3];
  float mean = s * (1.f / 1024.f);
  float var = s2 * (1.f / 1024.f) - mean * mean;
  float rinv = rsqrtf(var + 1e-5f);
#pragma unroll
  for (int j = 0; j < 4; ++j) {
    int c = t * 4 + j;
    float lnv = (x[j] - mean) * rinv * g[c] + bt[c];
    float pv = poi[b * 1024 + c];
    out[b * 2048 + c] = pv;
    out[b * 2048 + 1024 + c] = pv + lnv;
  }
}

// ---------------- host launch ----------------
extern "C" void kernel_launch(void* const* d_in, const int* in_sizes, int n_in,
                              void* d_out, int out_size, void* d_ws, size_t ws_size,
                              hipStream_t stream)
{
  const float* seq_emb  = (const float*)d_in[0];
  const float* seq_mask = (const float*)d_in[1];
  const float* his_emb  = (const float*)d_in[2];
  const float* his_mask = (const float*)d_in[3];
  const float* sa_wq = (const float*)d_in[4];
  const float* sa_bq = (const float*)d_in[5];
  const float* sa_wk = (const float*)d_in[6];
  const float* sa_bk = (const float*)d_in[7];
  const float* sa_wv = (const float*)d_in[8];
  const float* sa_bv = (const float*)d_in[9];
  const float* sa_wo = (const float*)d_in[10];
  const float* sa_bo = (const float*)d_in[11];
  const float* sn_g  = (const float*)d_in[12];
  const float* sn_b  = (const float*)d_in[13];
  const float* aa_wq = (const float*)d_in[14];
  const float* aa_wk = (const float*)d_in[15];
  const float* aa_wv = (const float*)d_in[16];
  const float* aa_wo = (const float*)d_in[17];
  const float* aa_wa = (const float*)d_in[18];
  const float* ln_g  = (const float*)d_in[19];
  const float* ln_b  = (const float*)d_in[20];
  float* out = (float*)d_out;

  char* p = (char*)d_ws;
  size_t off = 0;
  auto alloc = [&](size_t bytes) -> void* {
    void* r = p + off;
    off += (bytes + 255) & ~(size_t)255;
    return r;
  };
  unsigned short* seqb = (unsigned short*)alloc((size_t)16384 * 1024 * 2);
  unsigned short* hisb = (unsigned short*)alloc((size_t)65536 * 1024 * 2);
  unsigned short* wqT  = (unsigned short*)alloc((size_t)1024 * 1024 * 2);
  unsigned short* wkT  = (unsigned short*)alloc((size_t)1024 * 1024 * 2);
  unsigned short* wvT  = (unsigned short*)alloc((size_t)1024 * 1024 * 2);
  unsigned short* woT  = (unsigned short*)alloc((size_t)1024 * 1024 * 2);
  unsigned short* awkT = (unsigned short*)alloc((size_t)1024 * 1024 * 2);
  unsigned short* qb   = (unsigned short*)alloc((size_t)16384 * 1024 * 2);
  unsigned short* kb   = (unsigned short*)alloc((size_t)16384 * 1024 * 2);
  unsigned short* vTb  = (unsigned short*)alloc((size_t)16384 * 1024 * 2);
  unsigned short* ctxb = (unsigned short*)alloc((size_t)16384 * 1024 * 2);
  unsigned short* saob = (unsigned short*)alloc((size_t)16384 * 1024 * 2);
  float* poi_sum = (float*)alloc((size_t)32 * 1024 * 4);
  float* poi     = (float*)alloc((size_t)32 * 1024 * 4);
  float* aqb     = (float*)alloc((size_t)32 * 1024 * 4);
  float* ascore  = (float*)alloc((size_t)32 * 2048 * 4);
  float* hwb     = (float*)alloc((size_t)32 * 1024 * 4);
  float* actx    = (float*)alloc((size_t)32 * 1024 * 4);
  float* aaout   = (float*)alloc((size_t)32 * 1024 * 4);
  if (off > ws_size) return;  // insufficient workspace; bail (will fail validation)

  hipMemsetAsync(poi_sum, 0, (size_t)32 * 1024 * 4, stream);
  hipMemsetAsync(ascore, 0, (size_t)32 * 2048 * 4, stream);
  hipMemsetAsync(hwb, 0, (size_t)32 * 1024 * 4, stream);

  cvt_bf16<<<2048, 256, 0, stream>>>(seq_emb, seqb, 16384 * 1024 / 4);
  cvt_bf16<<<2048, 256, 0, stream>>>(his_emb, hisb, 65536 * 1024 / 4);
  dim3 tg(16, 16);
  tcvt<<<tg, 256, 0, stream>>>(sa_wq, wqT);
  tcvt<<<tg, 256, 0, stream>>>(sa_wk, wkT);
  tcvt<<<tg, 256, 0, stream>>>(sa_wv, wvT);
  tcvt<<<tg, 256, 0, stream>>>(sa_wo, woT);
  tcvt<<<tg, 256, 0, stream>>>(aa_wk, awkT);

  gemm128<0><<<dim3(8, 128), 256, 0, stream>>>(seqb, wqT, sa_bq, qb, nullptr, nullptr, nullptr);
  gemm128<0><<<dim3(8, 128), 256, 0, stream>>>(seqb, wkT, sa_bk, kb, nullptr, nullptr, nullptr);
  gemm128<1><<<dim3(8, 128), 256, 0, stream>>>(seqb, wvT, sa_bv, vTb, nullptr, nullptr, nullptr);

  attn_kernel<<<dim3(16, 4, 32), 256, 99328, stream>>>(qb, kb, vTb, seq_mask, ctxb, out + 65536);

  gemm128<0><<<dim3(8, 128), 256, 0, stream>>>(ctxb, woT, sa_bo, saob, nullptr, nullptr, nullptr);
  ln_mean<<<dim3(8, 32), 256, 0, stream>>>(saob, sn_g, sn_b, seq_mask, poi_sum);
  finalize_poi<<<128, 256, 0, stream>>>(poi_sum, poi);
  gemv32<<<dim3(4, 32), 256, 0, stream>>>(poi, aa_wq, aqb);

  gemm128<2><<<dim3(8, 512), 256, 0, stream>>>(hisb, awkT, nullptr, nullptr, aqb, aa_wa, ascore);
  softmax_his<<<32, 256, 0, stream>>>(ascore, his_mask);
  hw_kernel<<<dim3(8, 32), 256, 0, stream>>>(ascore, hisb, hwb);
  gemv32<<<dim3(4, 32), 256, 0, stream>>>(hwb, aa_wv, actx);
  gemv32<<<dim3(4, 32), 256, 0, stream>>>(actx, aa_wo, aaout);
  final_kernel<<<32, 256, 0, stream>>>(aaout, ln_g, ln_b, poi, out);
}

// Round 2
// 823.203 us; speedup vs baseline: 1.1816x; 1.1816x over previous
//
#include <hip/hip_runtime.h>

#define NEGV (-1000000000.0f)

typedef __attribute__((ext_vector_type(8))) short sh8;
typedef __attribute__((ext_vector_type(4))) short sh4;
typedef __attribute__((ext_vector_type(8))) __bf16 bf16x8;
typedef __attribute__((ext_vector_type(4))) float f32x4;

__device__ __forceinline__ float b2f(unsigned short u) {
  unsigned v = ((unsigned)u) << 16;
  return __builtin_bit_cast(float, v);
}
__device__ __forceinline__ unsigned short f2b(float f) {
  unsigned x = __builtin_bit_cast(unsigned, f);
  unsigned r = (x + 0x7fffu + ((x >> 16) & 1u)) >> 16;
  return (unsigned short)r;
}
__device__ __forceinline__ void g2l16(const void* g, void* l) {
  __builtin_amdgcn_global_load_lds((const __attribute__((address_space(1))) unsigned int*)g,
                                   (__attribute__((address_space(3))) unsigned int*)l, 16, 0, 0);
}
__device__ __forceinline__ f32x4 mfma16(bf16x8 a, bf16x8 b, f32x4 c) {
  return __builtin_amdgcn_mfma_f32_16x16x32_bf16(a, b, c, 0, 0, 0);
}
__device__ __forceinline__ float fast_tanh(float x) {
  x = fminf(fmaxf(x, -15.f), 15.f);
  float e = __expf(2.f * x);
  return (e - 1.f) / (e + 1.f);
}

// ---------------- conversion kernels ----------------
__global__ void cvt_bf16(const float* __restrict__ src, unsigned short* __restrict__ dst, int n4) {
  int i = blockIdx.x * blockDim.x + threadIdx.x;
  int stride = gridDim.x * blockDim.x;
  for (; i < n4; i += stride) {
    float4 v = ((const float4*)src)[i];
    sh4 o;
    o[0] = (short)f2b(v.x); o[1] = (short)f2b(v.y);
    o[2] = (short)f2b(v.z); o[3] = (short)f2b(v.w);
    ((sh4*)dst)[i] = o;
  }
}

// dst[n][k] = bf16(src[k][n]) for 1024x1024
__global__ void tcvt(const float* __restrict__ src, unsigned short* __restrict__ dst) {
  __shared__ float tile[64][65];
  int bx = blockIdx.x, by = blockIdx.y;
  int tx = threadIdx.x & 63, ty = threadIdx.x >> 6;
#pragma unroll
  for (int i = 0; i < 16; ++i) {
    int r = i * 4 + ty;
    tile[r][tx] = src[(size_t)(by * 64 + r) * 1024 + bx * 64 + tx];
  }
  __syncthreads();
#pragma unroll
  for (int i = 0; i < 16; ++i) {
    int r = i * 4 + ty;
    dst[(size_t)(bx * 64 + r) * 1024 + by * 64 + tx] = f2b(tile[tx][r]);
  }
}

// ---------------- 128x128 bf16 MFMA GEMM, K=N=1024, nbx=8 fixed ----------------
// A: M x 1024 bf16, Bt: 1024 x 1024 bf16 (n-major: Bt[n][k])
// EPI 0: C=bf16(acc+bias) row-major; EPI 1: v-transposed write; EPI 2: tanh-dot-atomic score
template<int EPI>
__global__ __launch_bounds__(256, 2)
void gemm128(const unsigned short* __restrict__ A, const unsigned short* __restrict__ Bt,
             const float* __restrict__ bias, unsigned short* __restrict__ C,
             const float* __restrict__ aq, const float* __restrict__ wa,
             float* __restrict__ sc)
{
  __shared__ unsigned short ldsA[128 * 32];
  __shared__ unsigned short ldsB[128 * 32];
  const int tid = threadIdx.x;
  const int w = tid >> 6, l = tid & 63;
  const int wr = w >> 1, wc = w & 1;
  const int lr = l & 15, lk8 = (l >> 4) * 8;
  // XCD-aware swizzle: blocks with the same by (A-panel) land on the same XCD
  const int wg = blockIdx.x;
  const int cpx = gridDim.x >> 3;
  const int wgid = (wg & 7) * cpx + (wg >> 3);
  const int bx = wgid & 7, by = wgid >> 3;
  const int m0 = by * 128;
  const int n0 = bx * 128;

  f32x4 acc[4][4] = {};

  const int srow = tid >> 2;
  const int scol = (tid & 3) * 8;
  const unsigned short* gA0 = A + (size_t)(m0 + srow) * 1024 + scol;
  const unsigned short* gB0 = Bt + (size_t)(n0 + srow) * 1024 + scol;
  unsigned short* lA = &ldsA[w * 512];
  unsigned short* lB = &ldsB[w * 512];

  for (int kt = 0; kt < 32; ++kt) {
    const int k0 = kt * 32;
    g2l16(gA0 + k0, lA);
    g2l16(gA0 + 64 * 1024 + k0, lA + 2048);
    g2l16(gB0 + k0, lB);
    g2l16(gB0 + 64 * 1024 + k0, lB + 2048);
    __syncthreads();
    bf16x8 af[4], bf[4];
#pragma unroll
    for (int i = 0; i < 4; ++i)
      af[i] = *(const bf16x8*)&ldsA[(wr * 64 + i * 16 + lr) * 32 + lk8];
#pragma unroll
    for (int j = 0; j < 4; ++j)
      bf[j] = *(const bf16x8*)&ldsB[(wc * 64 + j * 16 + lr) * 32 + lk8];
#pragma unroll
    for (int i = 0; i < 4; ++i)
#pragma unroll
      for (int j = 0; j < 4; ++j)
        acc[i][j] = mfma16(af[i], bf[j], acc[i][j]);
    __syncthreads();
  }

  if (EPI == 0) {
#pragma unroll
    for (int j = 0; j < 4; ++j) {
      int col = n0 + wc * 64 + j * 16 + lr;
      float bv = bias[col];
#pragma unroll
      for (int i = 0; i < 4; ++i) {
        int rowb = m0 + wr * 64 + i * 16 + (l >> 4) * 4;
#pragma unroll
        for (int r = 0; r < 4; ++r)
          C[(size_t)(rowb + r) * 1024 + col] = f2b(acc[i][j][r] + bv);
      }
    }
  } else if (EPI == 1) {
#pragma unroll
    for (int j = 0; j < 4; ++j) {
      int col = n0 + wc * 64 + j * 16 + lr;
      float bv = bias[col];
      int h = col >> 8, d = col & 255;
#pragma unroll
      for (int i = 0; i < 4; ++i) {
        int rowb = m0 + wr * 64 + i * 16 + (l >> 4) * 4;
        int bb = rowb >> 9, ll = rowb & 511;
        size_t base = ((size_t)(bb * 4 + h) * 256 + d) * 512 + ll;
#pragma unroll
        for (int r = 0; r < 4; ++r)
          C[base + r] = f2b(acc[i][j][r] + bv);
      }
    }
  } else {
    const int bb = m0 >> 11;
#pragma unroll
    for (int i = 0; i < 4; ++i) {
      float rp[4] = {0.f, 0.f, 0.f, 0.f};
#pragma unroll
      for (int j = 0; j < 4; ++j) {
        int col = n0 + wc * 64 + j * 16 + lr;
        float wav = wa[col];
        float aqv = aq[bb * 1024 + col];
#pragma unroll
        for (int r = 0; r < 4; ++r)
          rp[r] += wav * fast_tanh(acc[i][j][r] + aqv);
      }
#pragma unroll
      for (int off = 1; off < 16; off <<= 1)
#pragma unroll
        for (int r = 0; r < 4; ++r)
          rp[r] += __shfl_xor(rp[r], off, 64);
      if (lr == 0) {
        int rowb = m0 + wr * 64 + i * 16 + (l >> 4) * 4;
#pragma unroll
        for (int r = 0; r < 4; ++r)
          atomicAdd(&sc[rowb + r], rp[r]);
      }
    }
  }
}

// ---------------- fused attention (register softmax, 34.3KB LDS) ----------------
// LDS: Qs u16[32][264] UNION Ps u16[32][520] at 0; redm f32[4][32] @33280; reds @33792
__global__ __launch_bounds__(256, 4)
void attn_kernel(const unsigned short* __restrict__ q, const unsigned short* __restrict__ k,
                 const unsigned short* __restrict__ vT, const float* __restrict__ seq_mask,
                 unsigned short* __restrict__ ctx, float* __restrict__ attn_out)
{
  __shared__ char smem[34304];
  unsigned short* Qs = (unsigned short*)smem;
  unsigned short* Ps = (unsigned short*)smem;
  float* redm = (float*)(smem + 33280);
  float* reds = (float*)(smem + 33792);
  const int t = threadIdx.x, w = t >> 6, l = t & 63;
  const int lr = l & 15, g = l >> 4, lk8 = g * 8;
  // swizzle: all 16 q-tiles of a (b,h) pair on the same XCD (shared K/V panel in L2)
  const int wg = blockIdx.x;
  const int wgid = (wg & 7) * 256 + (wg >> 3);
  const int qt = wgid & 15, bh = wgid >> 4;
  const int h = bh & 3, b = bh >> 2;
  const int l0 = qt * 32;

  for (int idx = t; idx < 32 * 32; idx += 256) {
    int r = idx >> 5, ch = (idx & 31) * 8;
    *(sh8*)&Qs[r * 264 + ch] =
        *(const sh8*)&q[((size_t)(b * 512 + l0 + r)) * 1024 + h * 256 + ch];
  }
  __syncthreads();

  // QK^T : wave w handles kj in [w*128, w*128+128)
  f32x4 accs[2][8] = {};
  const unsigned short* kbase = k + ((size_t)b * 512) * 1024 + h * 256;
#pragma unroll
  for (int ds = 0; ds < 8; ++ds) {
    int d0 = ds * 32;
    bf16x8 a0 = *(const bf16x8*)&Qs[lr * 264 + d0 + lk8];
    bf16x8 a1 = *(const bf16x8*)&Qs[(16 + lr) * 264 + d0 + lk8];
#pragma unroll
    for (int j = 0; j < 8; ++j) {
      int kj = w * 128 + j * 16 + lr;
      bf16x8 bb = *(const bf16x8*)&kbase[(size_t)kj * 1024 + d0 + lk8];
      accs[0][j] = mfma16(a0, bb, accs[0][j]);
      accs[1][j] = mfma16(a1, bb, accs[1][j]);
    }
  }

  // mask + scale (C layout: row = i*16 + g*4 + r, col = w*128 + j*16 + lr)
#pragma unroll
  for (int j = 0; j < 8; ++j) {
    int col = w * 128 + j * 16 + lr;
    float mv = seq_mask[b * 512 + col];
    bool msk = (mv == 0.f);
#pragma unroll
    for (int i = 0; i < 2; ++i)
#pragma unroll
      for (int r = 0; r < 4; ++r)
        accs[i][j][r] = msk ? NEGV : accs[i][j][r] * 0.0625f;
  }

  // row max: per-lane over j, then across the 16 col-lanes, then across waves via LDS
  float mx[2][4], sm[2][4];
#pragma unroll
  for (int i = 0; i < 2; ++i)
#pragma unroll
    for (int r = 0; r < 4; ++r) {
      float m = accs[i][0][r];
#pragma unroll
      for (int j = 1; j < 8; ++j) m = fmaxf(m, accs[i][j][r]);
      mx[i][r] = m;
    }
#pragma unroll
  for (int off = 1; off < 16; off <<= 1)
#pragma unroll
    for (int i = 0; i < 2; ++i)
#pragma unroll
      for (int r = 0; r < 4; ++r)
        mx[i][r] = fmaxf(mx[i][r], __shfl_xor(mx[i][r], off, 64));
  if (lr == 0) {
#pragma unroll
    for (int i = 0; i < 2; ++i)
#pragma unroll
      for (int r = 0; r < 4; ++r)
        redm[w * 32 + i * 16 + g * 4 + r] = mx[i][r];
  }
  __syncthreads();
#pragma unroll
  for (int i = 0; i < 2; ++i)
#pragma unroll
    for (int r = 0; r < 4; ++r) {
      int row = i * 16 + g * 4 + r;
      mx[i][r] = fmaxf(fmaxf(redm[row], redm[32 + row]),
                       fmaxf(redm[64 + row], redm[96 + row]));
      sm[i][r] = 0.f;
    }

  // exp + row sum
#pragma unroll
  for (int i = 0; i < 2; ++i)
#pragma unroll
    for (int j = 0; j < 8; ++j)
#pragma unroll
      for (int r = 0; r < 4; ++r) {
        float p = __expf(accs[i][j][r] - mx[i][r]);
        accs[i][j][r] = p;
        sm[i][r] += p;
      }
#pragma unroll
  for (int off = 1; off < 16; off <<= 1)
#pragma unroll
    for (int i = 0; i < 2; ++i)
#pragma unroll
      for (int r = 0; r < 4; ++r)
        sm[i][r] += __shfl_xor(sm[i][r], off, 64);
  if (lr == 0) {
#pragma unroll
    for (int i = 0; i < 2; ++i)
#pragma unroll
      for (int r = 0; r < 4; ++r)
        reds[w * 32 + i * 16 + g * 4 + r] = sm[i][r];
  }
  __syncthreads();
#pragma unroll
  for (int i = 0; i < 2; ++i)
#pragma unroll
    for (int r = 0; r < 4; ++r) {
      int row = i * 16 + g * 4 + r;
      float s = reds[row] + reds[32 + row] + reds[64 + row] + reds[96 + row];
      sm[i][r] = 1.f / s;
    }

  // write P (bf16, LDS; aliases Qs which is dead now) + attn_weight for h=0
#pragma unroll
  for (int i = 0; i < 2; ++i)
#pragma unroll
    for (int j = 0; j < 8; ++j) {
      int col = w * 128 + j * 16 + lr;
#pragma unroll
      for (int r = 0; r < 4; ++r) {
        int row = i * 16 + g * 4 + r;
        float pn = accs[i][j][r] * sm[i][r];
        Ps[row * 520 + col] = f2b(pn);
        if (h == 0)
          attn_out[((size_t)(b * 512 + l0 + row)) * 512 + col] = pn;
      }
    }
  __syncthreads();

  // PV : wave w handles d in [w*64, w*64+64)
  f32x4 acco[2][4] = {};
  const unsigned short* vbase = vT + ((size_t)(b * 4 + h)) * 256 * 512;
#pragma unroll
  for (int ks = 0; ks < 16; ++ks) {
    int kj0 = ks * 32;
    bf16x8 a0 = *(const bf16x8*)&Ps[lr * 520 + kj0 + lk8];
    bf16x8 a1 = *(const bf16x8*)&Ps[(16 + lr) * 520 + kj0 + lk8];
#pragma unroll
    for (int j = 0; j < 4; ++j) {
      int d = w * 64 + j * 16 + lr;
      bf16x8 bb = *(const bf16x8*)&vbase[(size_t)d * 512 + kj0 + lk8];
      acco[0][j] = mfma16(a0, bb, acco[0][j]);
      acco[1][j] = mfma16(a1, bb, acco[1][j]);
    }
  }
#pragma unroll
  for (int i = 0; i < 2; ++i)
#pragma unroll
    for (int j = 0; j < 4; ++j) {
      int col = w * 64 + j * 16 + lr;
#pragma unroll
      for (int r = 0; r < 4; ++r) {
        int row = i * 16 + g * 4 + r;
        ctx[((size_t)(b * 512 + l0 + row)) * 1024 + h * 256 + col] = f2b(acco[i][j][r]);
      }
    }
}

// ---------------- LN + masked mean over L ----------------
__global__ __launch_bounds__(256)
void ln_mean(const unsigned short* __restrict__ sa, const float* __restrict__ g,
             const float* __restrict__ bt, const float* __restrict__ mask,
             float* __restrict__ poi_sum)
{
  const int b = blockIdx.y, ch = blockIdx.x;
  const int t = threadIdx.x, w = t >> 6, l = t & 63;
  float gg[16], bb[16];
#pragma unroll
  for (int j = 0; j < 16; ++j) { gg[j] = g[l * 16 + j]; bb[j] = bt[l * 16 + j]; }
  float accv[16];
#pragma unroll
  for (int j = 0; j < 16; ++j) accv[j] = 0.f;
  for (int rr = 0; rr < 16; ++rr) {
    int row = ch * 64 + w * 16 + rr;
    const unsigned short* rp = sa + ((size_t)(b * 512 + row)) * 1024 + l * 16;
    float x[16];
    sh8 v0 = *(const sh8*)rp;
    sh8 v1 = *(const sh8*)(rp + 8);
#pragma unroll
    for (int j = 0; j < 8; ++j) {
      x[j] = b2f((unsigned short)v0[j]);
      x[8 + j] = b2f((unsigned short)v1[j]);
    }
    float s = 0.f, s2 = 0.f;
#pragma unroll
    for (int j = 0; j < 16; ++j) { s += x[j]; s2 += x[j] * x[j]; }
#pragma unroll
    for (int off = 1; off < 64; off <<= 1) {
      s += __shfl_xor(s, off, 64);
      s2 += __shfl_xor(s2, off, 64);
    }
    float mean = s * (1.f / 1024.f);
    float var = s2 * (1.f / 1024.f) - mean * mean;
    float rinv = rsqrtf(var + 1e-5f);
    float mk = mask[b * 512 + row];
#pragma unroll
    for (int j = 0; j < 16; ++j) accv[j] += ((x[j] - mean) * rinv * gg[j] + bb[j]) * mk;
  }
#pragma unroll
  for (int j = 0; j < 16; ++j) atomicAdd(&poi_sum[b * 1024 + l * 16 + j], accv[j]);
}

__global__ void finalize_poi(const float* __restrict__ ps, float* __restrict__ poi) {
  int i = blockIdx.x * 256 + threadIdx.x;
  if (i < 32 * 1024) poi[i] = ps[i] * (1.f / 512.f);
}

// out[b][n] = sum_d in[b][d] * W[d][n]
__global__ __launch_bounds__(256)
void gemv32(const float* __restrict__ in, const float* __restrict__ W, float* __restrict__ out)
{
  const int b = blockIdx.y;
  const int n = blockIdx.x * 256 + threadIdx.x;
  const float* ib = in + b * 1024;
  float acc = 0.f;
  for (int d = 0; d < 1024; d += 4) {
    acc += ib[d]     * W[(size_t)d * 1024 + n]
         + ib[d + 1] * W[(size_t)(d + 1) * 1024 + n]
         + ib[d + 2] * W[(size_t)(d + 2) * 1024 + n]
         + ib[d + 3] * W[(size_t)(d + 3) * 1024 + n];
  }
  out[b * 1024 + n] = acc;
}

__global__ __launch_bounds__(256)
void softmax_his(float* __restrict__ sc, const float* __restrict__ mask)
{
  __shared__ float red[4];
  const int b = blockIdx.x, t = threadIdx.x, w = t >> 6, l = t & 63;
  float v[8];
  float mx = -3.0e38f;
#pragma unroll
  for (int i = 0; i < 8; ++i) {
    int kk = t + i * 256;
    float s = (mask[b * 2048 + kk] == 0.f) ? NEGV : sc[b * 2048 + kk];
    v[i] = s;
    mx = fmaxf(mx, s);
  }
#pragma unroll
  for (int off = 1; off < 64; off <<= 1) mx = fmaxf(mx, __shfl_xor(mx, off, 64));
  if (l == 0) red[w] = mx;
  __syncthreads();
  mx = fmaxf(fmaxf(red[0], red[1]), fmaxf(red[2], red[3]));
  float sum = 0.f;
#pragma unroll
  for (int i = 0; i < 8; ++i) { v[i] = __expf(v[i] - mx); sum += v[i]; }
#pragma unroll
  for (int off = 1; off < 64; off <<= 1) sum += __shfl_xor(sum, off, 64);
  __syncthreads();
  if (l == 0) red[w] = sum;
  __syncthreads();
  sum = red[0] + red[1] + red[2] + red[3];
  float inv = 1.f / sum;
#pragma unroll
  for (int i = 0; i < 8; ++i) sc[b * 2048 + t + i * 256] = v[i] * inv;
}

// hw[b][d] = sum_k aw[b][k] * his_bf16[b][k][d]
__global__ __launch_bounds__(256)
void hw_kernel(const float* __restrict__ aw, const unsigned short* __restrict__ his,
               float* __restrict__ hw)
{
  const int b = blockIdx.y, kc = blockIdx.x, t = threadIdx.x;
  const int cb = t * 4;
  float a0 = 0.f, a1 = 0.f, a2 = 0.f, a3 = 0.f;
  for (int kk = 0; kk < 256; ++kk) {
    int k = kc * 256 + kk;
    float wg = aw[b * 2048 + k];
    sh4 vv = *(const sh4*)&his[((size_t)(b * 2048 + k)) * 1024 + cb];
    a0 += wg * b2f((unsigned short)vv[0]);
    a1 += wg * b2f((unsigned short)vv[1]);
    a2 += wg * b2f((unsigned short)vv[2]);
    a3 += wg * b2f((unsigned short)vv[3]);
  }
  atomicAdd(&hw[b * 1024 + cb + 0], a0);
  atomicAdd(&hw[b * 1024 + cb + 1], a1);
  atomicAdd(&hw[b * 1024 + cb + 2], a2);
  atomicAdd(&hw[b * 1024 + cb + 3], a3);
}

__global__ __launch_bounds__(256)
void final_kernel(const float* __restrict__ aa_out, const float* __restrict__ g,
                  const float* __restrict__ bt, const float* __restrict__ poi,
                  float* __restrict__ out)
{
  __shared__ float r1[4], r2[4];
  const int b = blockIdx.x, t = threadIdx.x, w = t >> 6, l = t & 63;
  float x[4];
#pragma unroll
  for (int j = 0; j < 4; ++j) x[j] = aa_out[b * 1024 + t * 4 + j];
  float s = 0.f, s2 = 0.f;
#pragma unroll
  for (int j = 0; j < 4; ++j) { s += x[j]; s2 += x[j] * x[j]; }
#pragma unroll
  for (int off = 1; off < 64; off <<= 1) {
    s += __shfl_xor(s, off, 64);
    s2 += __shfl_xor(s2, off, 64);
  }
  if (l == 0) { r1[w] = s; r2[w] = s2; }
  __syncthreads();
  s = r1[0] + r1[1] + r1[2] + r1[3];
  s2 = r2[0] + r2[1] + r2[2] + r2[3];
  float mean = s * (1.f / 1024.f);
  float var = s2 * (1.f / 1024.f) - mean * mean;
  float rinv = rsqrtf(var + 1e-5f);
#pragma unroll
  for (int j = 0; j < 4; ++j) {
    int c = t * 4 + j;
    float lnv = (x[j] - mean) * rinv * g[c] + bt[c];
    float pv = poi[b * 1024 + c];
    out[b * 2048 + c] = pv;
    out[b * 2048 + 1024 + c] = pv + lnv;
  }
}

// ---------------- host launch ----------------
extern "C" void kernel_launch(void* const* d_in, const int* in_sizes, int n_in,
                              void* d_out, int out_size, void* d_ws, size_t ws_size,
                              hipStream_t stream)
{
  const float* seq_emb  = (const float*)d_in[0];
  const float* seq_mask = (const float*)d_in[1];
  const float* his_emb  = (const float*)d_in[2];
  const float* his_mask = (const float*)d_in[3];
  const float* sa_wq = (const float*)d_in[4];
  const float* sa_bq = (const float*)d_in[5];
  const float* sa_wk = (const float*)d_in[6];
  const float* sa_bk = (const float*)d_in[7];
  const float* sa_wv = (const float*)d_in[8];
  const float* sa_bv = (const float*)d_in[9];
  const float* sa_wo = (const float*)d_in[10];
  const float* sa_bo = (const float*)d_in[11];
  const float* sn_g  = (const float*)d_in[12];
  const float* sn_b  = (const float*)d_in[13];
  const float* aa_wq = (const float*)d_in[14];
  const float* aa_wk = (const float*)d_in[15];
  const float* aa_wv = (const float*)d_in[16];
  const float* aa_wo = (const float*)d_in[17];
  const float* aa_wa = (const float*)d_in[18];
  const float* ln_g  = (const float*)d_in[19];
  const float* ln_b  = (const float*)d_in[20];
  float* out = (float*)d_out;

  char* p = (char*)d_ws;
  size_t off = 0;
  auto alloc = [&](size_t bytes) -> void* {
    void* r = p + off;
    off += (bytes + 255) & ~(size_t)255;
    return r;
  };
  unsigned short* seqb = (unsigned short*)alloc((size_t)16384 * 1024 * 2);
  unsigned short* hisb = (unsigned short*)alloc((size_t)65536 * 1024 * 2);
  unsigned short* wqT  = (unsigned short*)alloc((size_t)1024 * 1024 * 2);
  unsigned short* wkT  = (unsigned short*)alloc((size_t)1024 * 1024 * 2);
  unsigned short* wvT  = (unsigned short*)alloc((size_t)1024 * 1024 * 2);
  unsigned short* woT  = (unsigned short*)alloc((size_t)1024 * 1024 * 2);
  unsigned short* awkT = (unsigned short*)alloc((size_t)1024 * 1024 * 2);
  unsigned short* qb   = (unsigned short*)alloc((size_t)16384 * 1024 * 2);
  unsigned short* kb   = (unsigned short*)alloc((size_t)16384 * 1024 * 2);
  unsigned short* vTb  = (unsigned short*)alloc((size_t)16384 * 1024 * 2);
  unsigned short* ctxb = (unsigned short*)alloc((size_t)16384 * 1024 * 2);
  unsigned short* saob = (unsigned short*)alloc((size_t)16384 * 1024 * 2);
  float* poi_sum = (float*)alloc((size_t)32 * 1024 * 4);
  float* poi     = (float*)alloc((size_t)32 * 1024 * 4);
  float* aqb     = (float*)alloc((size_t)32 * 1024 * 4);
  float* ascore  = (float*)alloc((size_t)32 * 2048 * 4);
  float* hwb     = (float*)alloc((size_t)32 * 1024 * 4);
  float* actx    = (float*)alloc((size_t)32 * 1024 * 4);
  float* aaout   = (float*)alloc((size_t)32 * 1024 * 4);
  if (off > ws_size) return;  // insufficient workspace; bail (will fail validation)

  hipMemsetAsync(poi_sum, 0, (size_t)32 * 1024 * 4, stream);
  hipMemsetAsync(ascore, 0, (size_t)32 * 2048 * 4, stream);
  hipMemsetAsync(hwb, 0, (size_t)32 * 1024 * 4, stream);

  cvt_bf16<<<2048, 256, 0, stream>>>(seq_emb, seqb, 16384 * 1024 / 4);
  cvt_bf16<<<2048, 256, 0, stream>>>(his_emb, hisb, 65536 * 1024 / 4);
  dim3 tg(16, 16);
  tcvt<<<tg, 256, 0, stream>>>(sa_wq, wqT);
  tcvt<<<tg, 256, 0, stream>>>(sa_wk, wkT);
  tcvt<<<tg, 256, 0, stream>>>(sa_wv, wvT);
  tcvt<<<tg, 256, 0, stream>>>(sa_wo, woT);
  tcvt<<<tg, 256, 0, stream>>>(aa_wk, awkT);

  gemm128<0><<<1024, 256, 0, stream>>>(seqb, wqT, sa_bq, qb, nullptr, nullptr, nullptr);
  gemm128<0><<<1024, 256, 0, stream>>>(seqb, wkT, sa_bk, kb, nullptr, nullptr, nullptr);
  gemm128<1><<<1024, 256, 0, stream>>>(seqb, wvT, sa_bv, vTb, nullptr, nullptr, nullptr);

  attn_kernel<<<2048, 256, 0, stream>>>(qb, kb, vTb, seq_mask, ctxb, out + 65536);

  gemm128<0><<<1024, 256, 0, stream>>>(ctxb, woT, sa_bo, saob, nullptr, nullptr, nullptr);
  ln_mean<<<dim3(8, 32), 256, 0, stream>>>(saob, sn_g, sn_b, seq_mask, poi_sum);
  finalize_poi<<<128, 256, 0, stream>>>(poi_sum, poi);
  gemv32<<<dim3(4, 32), 256, 0, stream>>>(poi, aa_wq, aqb);

  gemm128<2><<<4096, 256, 0, stream>>>(hisb, awkT, nullptr, nullptr, aqb, aa_wa, ascore);
  softmax_his<<<32, 256, 0, stream>>>(ascore, his_mask);
  hw_kernel<<<dim3(8, 32), 256, 0, stream>>>(ascore, hisb, hwb);
  gemv32<<<dim3(4, 32), 256, 0, stream>>>(hwb, aa_wv, actx);
  gemv32<<<dim3(4, 32), 256, 0, stream>>>(actx, aa_wo, aaout);
  final_kernel<<<32, 256, 0, stream>>>(aaout, ln_g, ln_b, poi, out);
}

// Round 3
// 822.547 us; speedup vs baseline: 1.1825x; 1.0008x over previous
//
#include <hip/hip_runtime.h>

#define NEGV (-1000000000.0f)

typedef __attribute__((ext_vector_type(8))) short sh8;
typedef __attribute__((ext_vector_type(4))) short sh4;
typedef __attribute__((ext_vector_type(8))) __bf16 bf16x8;
typedef __attribute__((ext_vector_type(4))) float f32x4;

__device__ __forceinline__ float b2f(unsigned short u) {
  unsigned v = ((unsigned)u) << 16;
  return __builtin_bit_cast(float, v);
}
__device__ __forceinline__ unsigned short f2b(float f) {
  unsigned x = __builtin_bit_cast(unsigned, f);
  unsigned r = (x + 0x7fffu + ((x >> 16) & 1u)) >> 16;
  return (unsigned short)r;
}
__device__ __forceinline__ void g2l16(const void* g, void* l) {
  __builtin_amdgcn_global_load_lds((const __attribute__((address_space(1))) unsigned int*)g,
                                   (__attribute__((address_space(3))) unsigned int*)l, 16, 0, 0);
}
__device__ __forceinline__ f32x4 mfma16(bf16x8 a, bf16x8 b, f32x4 c) {
  return __builtin_amdgcn_mfma_f32_16x16x32_bf16(a, b, c, 0, 0, 0);
}
__device__ __forceinline__ float fast_tanh(float x) {
  x = fminf(fmaxf(x, -15.f), 15.f);
  float e = __expf(2.f * x);
  return (e - 1.f) / (e + 1.f);
}

// ---------------- conversion kernels ----------------
__global__ void cvt_bf16(const float* __restrict__ src, unsigned short* __restrict__ dst, int n4) {
  int i = blockIdx.x * blockDim.x + threadIdx.x;
  int stride = gridDim.x * blockDim.x;
  for (; i < n4; i += stride) {
    float4 v = ((const float4*)src)[i];
    sh4 o;
    o[0] = (short)f2b(v.x); o[1] = (short)f2b(v.y);
    o[2] = (short)f2b(v.z); o[3] = (short)f2b(v.w);
    ((sh4*)dst)[i] = o;
  }
}

// dst[n][k] = bf16(src[k][n]) for 1024x1024
__global__ void tcvt(const float* __restrict__ src, unsigned short* __restrict__ dst) {
  __shared__ float tile[64][65];
  int bx = blockIdx.x, by = blockIdx.y;
  int tx = threadIdx.x & 63, ty = threadIdx.x >> 6;
#pragma unroll
  for (int i = 0; i < 16; ++i) {
    int r = i * 4 + ty;
    tile[r][tx] = src[(size_t)(by * 64 + r) * 1024 + bx * 64 + tx];
  }
  __syncthreads();
#pragma unroll
  for (int i = 0; i < 16; ++i) {
    int r = i * 4 + ty;
    dst[(size_t)(bx * 64 + r) * 1024 + by * 64 + tx] = f2b(tile[tx][r]);
  }
}

// ---------------- 256x256 bf16 MFMA GEMM, K=1024, pipelined ring-4 LDS ----------------
// A: M x 1024 bf16 row-major. Bt: N x 1024 bf16 (n-major).
// 512 threads = 8 waves (2 wm x 4 wn); wave tile 128x64; acc[8][4] f32x4.
// K-tile = 32 (BK); LDS ring of 4 x 32KB (A-half0,A-half1,B-half0,B-half1 @8KB each).
// Prefetch distance 2 K-tiles; steady-state s_waitcnt vmcnt(4), never 0.
// EPI 0: row-major + bias (O0). EPI 1: fused QKV (q->O0, k->O1, v-transposed->O2,
//        biases b0,b1,b2). EPI 2: tanh-dot-atomic his-score (aq, wa, sc).
template<int EPI>
__global__ __launch_bounds__(512, 1)
void gemm256(const unsigned short* __restrict__ A, const unsigned short* __restrict__ Bt,
             int nbx,
             const float* __restrict__ b0, const float* __restrict__ b1,
             const float* __restrict__ b2,
             unsigned short* __restrict__ O0, unsigned short* __restrict__ O1,
             unsigned short* __restrict__ O2,
             const float* __restrict__ aq, const float* __restrict__ wa,
             float* __restrict__ sc)
{
  __shared__ char lds[131072];
  const int tid = threadIdx.x;
  const int w = tid >> 6, l = tid & 63;
  const int wm = w >> 2, wn = w & 3;
  const int lr = l & 15, g = l >> 4;
  const int kg16 = g * 16;

  // bijective XCD swizzle (gridDim.x % 8 == 0 for all our shapes)
  const int wg = blockIdx.x;
  const int cpx = gridDim.x >> 3;
  const int wgid = (wg & 7) * cpx + (wg >> 3);
  const int bx = wgid % nbx, by = wgid / nbx;
  const size_t m0 = (size_t)by * 256;
  const int n0 = bx * 256;

  f32x4 acc[8][4] = {};

  // staging: thread covers row (tid>>2) of a 128-row half, k-chunk (tid&3)*8
  const int srow = tid >> 2, sk = (tid & 3) * 8;
  const unsigned short* gA = A + (m0 + srow) * 1024 + sk;
  const unsigned short* gB = Bt + ((size_t)n0 + srow) * 1024 + sk;
  char* const sbase = lds + w * 1024;  // wave-uniform; HW adds lane*16

  // compute-side LDS byte offsets (within a 32KB buffer)
  const int aoff = (wm * 128 + lr) * 64 + kg16;           // + i*1024 per fragment row
  const int boff = 16384 + (wn * 64 + lr) * 64 + kg16;    // + j*1024 per fragment col

  // ---- prologue: stage K-tiles 0 and 1 ----
#pragma unroll
  for (int p = 0; p < 2; ++p) {
    const unsigned short* a = gA + p * 32;
    const unsigned short* b = gB + p * 32;
    char* base = sbase + (p << 15);
    g2l16(a, base);
    g2l16(a + 128 * 1024, base + 8192);
    g2l16(b, base + 16384);
    g2l16(b + 128 * 1024, base + 24576);
  }
  asm volatile("s_waitcnt vmcnt(4)" ::: "memory");
  __builtin_amdgcn_s_barrier();

#pragma unroll 1
  for (int kt = 0; kt < 32; ++kt) {
    const char* pb = lds + ((kt & 3) << 15);
    char* nb = sbase + (((kt + 2) & 3) << 15);
    bf16x8 af[4], bf[4];

    // ======== phase 0 ========
    if (kt < 30) {  // stage A-halves of kt+2
      const unsigned short* a = gA + (kt + 2) * 32;
      g2l16(a, nb);
      g2l16(a + 128 * 1024, nb + 8192);
    }
#pragma unroll
    for (int j = 0; j < 4; ++j) bf[j] = *(const bf16x8*)(pb + boff + j * 1024);
#pragma unroll
    for (int i = 0; i < 4; ++i) af[i] = *(const bf16x8*)(pb + aoff + i * 1024);
    __builtin_amdgcn_s_barrier();
    asm volatile("s_waitcnt lgkmcnt(0)" ::: "memory");
    __builtin_amdgcn_sched_barrier(0);
    __builtin_amdgcn_s_setprio(1);
#pragma unroll
    for (int i = 0; i < 4; ++i)
#pragma unroll
      for (int j = 0; j < 4; ++j)
        acc[i][j] = mfma16(af[i], bf[j], acc[i][j]);
    __builtin_amdgcn_s_setprio(0);
    __builtin_amdgcn_s_barrier();

    // ======== phase 1 ========
    if (kt < 30) {  // stage B-halves of kt+2
      const unsigned short* b = gB + (kt + 2) * 32;
      g2l16(b, nb + 16384);
      g2l16(b + 128 * 1024, nb + 24576);
    }
#pragma unroll
    for (int i = 0; i < 4; ++i) af[i] = *(const bf16x8*)(pb + aoff + (4 + i) * 1024);
    __builtin_amdgcn_s_barrier();
    asm volatile("s_waitcnt lgkmcnt(0)" ::: "memory");
    __builtin_amdgcn_sched_barrier(0);
    __builtin_amdgcn_s_setprio(1);
#pragma unroll
    for (int i = 0; i < 4; ++i)
#pragma unroll
      for (int j = 0; j < 4; ++j)
        acc[4 + i][j] = mfma16(af[i], bf[j], acc[4 + i][j]);
    __builtin_amdgcn_s_setprio(0);
    if (kt < 30) {
      asm volatile("s_waitcnt vmcnt(4)" ::: "memory");   // kt+1 resident, kt+2 in flight
    } else if (kt == 30) {
      asm volatile("s_waitcnt vmcnt(0)" ::: "memory");   // drain for last tile
    }
    __builtin_amdgcn_s_barrier();
  }

  // ======== epilogue ========
  if (EPI == 0) {
#pragma unroll
    for (int j = 0; j < 4; ++j) {
      int col = n0 + wn * 64 + j * 16 + lr;
      float bv = b0[col];
#pragma unroll
      for (int i = 0; i < 8; ++i) {
        size_t rowb = m0 + wm * 128 + i * 16 + g * 4;
#pragma unroll
        for (int r = 0; r < 4; ++r)
          O0[(rowb + r) * 1024 + col] = f2b(acc[i][j][r] + bv);
      }
    }
  } else if (EPI == 1) {
#pragma unroll
    for (int j = 0; j < 4; ++j) {
      int col3 = n0 + wn * 64 + j * 16 + lr;
      int part = col3 >> 10, c = col3 & 1023;
      float bv = (part == 0) ? b0[c] : (part == 1) ? b1[c] : b2[c];
      if (part < 2) {
        unsigned short* O = part == 0 ? O0 : O1;
#pragma unroll
        for (int i = 0; i < 8; ++i) {
          size_t rowb = m0 + wm * 128 + i * 16 + g * 4;
#pragma unroll
          for (int r = 0; r < 4; ++r)
            O[(rowb + r) * 1024 + c] = f2b(acc[i][j][r] + bv);
        }
      } else {  // v: transposed layout vT[(b*4+h)*256 + d][512] = v[b, l, h, d]
        int h = c >> 8, d = c & 255;
#pragma unroll
        for (int i = 0; i < 8; ++i) {
          size_t row = m0 + wm * 128 + i * 16 + g * 4;
          int bb = (int)(row >> 9), ll = (int)(row & 511);
          size_t base = ((size_t)(bb * 4 + h) * 256 + d) * 512 + ll;
#pragma unroll
          for (int r = 0; r < 4; ++r)
            O2[base + r] = f2b(acc[i][j][r] + bv);
        }
      }
    }
  } else {
    const int bb = (int)(m0 >> 11);
#pragma unroll
    for (int i = 0; i < 8; ++i) {
      float rp[4] = {0.f, 0.f, 0.f, 0.f};
#pragma unroll
      for (int j = 0; j < 4; ++j) {
        int col = n0 + wn * 64 + j * 16 + lr;
        float wav = wa[col];
        float aqv = aq[bb * 1024 + col];
#pragma unroll
        for (int r = 0; r < 4; ++r)
          rp[r] += wav * fast_tanh(acc[i][j][r] + aqv);
      }
#pragma unroll
      for (int off = 1; off < 16; off <<= 1)
#pragma unroll
        for (int r = 0; r < 4; ++r)
          rp[r] += __shfl_xor(rp[r], off, 64);
      if (lr == 0) {
        size_t rowb = m0 + wm * 128 + i * 16 + g * 4;
#pragma unroll
        for (int r = 0; r < 4; ++r)
          atomicAdd(&sc[rowb + r], rp[r]);
      }
    }
  }
}

// ---------------- fused attention (register softmax, 34.3KB LDS) ----------------
__global__ __launch_bounds__(256, 4)
void attn_kernel(const unsigned short* __restrict__ q, const unsigned short* __restrict__ k,
                 const unsigned short* __restrict__ vT, const float* __restrict__ seq_mask,
                 unsigned short* __restrict__ ctx, float* __restrict__ attn_out)
{
  __shared__ char smem[34304];
  unsigned short* Qs = (unsigned short*)smem;
  unsigned short* Ps = (unsigned short*)smem;
  float* redm = (float*)(smem + 33280);
  float* reds = (float*)(smem + 33792);
  const int t = threadIdx.x, w = t >> 6, l = t & 63;
  const int lr = l & 15, g = l >> 4, lk8 = g * 8;
  const int wg = blockIdx.x;
  const int wgid = (wg & 7) * 256 + (wg >> 3);
  const int qt = wgid & 15, bh = wgid >> 4;
  const int h = bh & 3, b = bh >> 2;
  const int l0 = qt * 32;

  for (int idx = t; idx < 32 * 32; idx += 256) {
    int r = idx >> 5, ch = (idx & 31) * 8;
    *(sh8*)&Qs[r * 264 + ch] =
        *(const sh8*)&q[((size_t)(b * 512 + l0 + r)) * 1024 + h * 256 + ch];
  }
  __syncthreads();

  f32x4 accs[2][8] = {};
  const unsigned short* kbase = k + ((size_t)b * 512) * 1024 + h * 256;
#pragma unroll
  for (int ds = 0; ds < 8; ++ds) {
    int d0 = ds * 32;
    bf16x8 a0 = *(const bf16x8*)&Qs[lr * 264 + d0 + lk8];
    bf16x8 a1 = *(const bf16x8*)&Qs[(16 + lr) * 264 + d0 + lk8];
#pragma unroll
    for (int j = 0; j < 8; ++j) {
      int kj = w * 128 + j * 16 + lr;
      bf16x8 bb = *(const bf16x8*)&kbase[(size_t)kj * 1024 + d0 + lk8];
      accs[0][j] = mfma16(a0, bb, accs[0][j]);
      accs[1][j] = mfma16(a1, bb, accs[1][j]);
    }
  }

#pragma unroll
  for (int j = 0; j < 8; ++j) {
    int col = w * 128 + j * 16 + lr;
    float mv = seq_mask[b * 512 + col];
    bool msk = (mv == 0.f);
#pragma unroll
    for (int i = 0; i < 2; ++i)
#pragma unroll
      for (int r = 0; r < 4; ++r)
        accs[i][j][r] = msk ? NEGV : accs[i][j][r] * 0.0625f;
  }

  float mx[2][4], sm[2][4];
#pragma unroll
  for (int i = 0; i < 2; ++i)
#pragma unroll
    for (int r = 0; r < 4; ++r) {
      float m = accs[i][0][r];
#pragma unroll
      for (int j = 1; j < 8; ++j) m = fmaxf(m, accs[i][j][r]);
      mx[i][r] = m;
    }
#pragma unroll
  for (int off = 1; off < 16; off <<= 1)
#pragma unroll
    for (int i = 0; i < 2; ++i)
#pragma unroll
      for (int r = 0; r < 4; ++r)
        mx[i][r] = fmaxf(mx[i][r], __shfl_xor(mx[i][r], off, 64));
  if (lr == 0) {
#pragma unroll
    for (int i = 0; i < 2; ++i)
#pragma unroll
      for (int r = 0; r < 4; ++r)
        redm[w * 32 + i * 16 + g * 4 + r] = mx[i][r];
  }
  __syncthreads();
#pragma unroll
  for (int i = 0; i < 2; ++i)
#pragma unroll
    for (int r = 0; r < 4; ++r) {
      int row = i * 16 + g * 4 + r;
      mx[i][r] = fmaxf(fmaxf(redm[row], redm[32 + row]),
                       fmaxf(redm[64 + row], redm[96 + row]));
      sm[i][r] = 0.f;
    }

#pragma unroll
  for (int i = 0; i < 2; ++i)
#pragma unroll
    for (int j = 0; j < 8; ++j)
#pragma unroll
      for (int r = 0; r < 4; ++r) {
        float p = __expf(accs[i][j][r] - mx[i][r]);
        accs[i][j][r] = p;
        sm[i][r] += p;
      }
#pragma unroll
  for (int off = 1; off < 16; off <<= 1)
#pragma unroll
    for (int i = 0; i < 2; ++i)
#pragma unroll
      for (int r = 0; r < 4; ++r)
        sm[i][r] += __shfl_xor(sm[i][r], off, 64);
  if (lr == 0) {
#pragma unroll
    for (int i = 0; i < 2; ++i)
#pragma unroll
      for (int r = 0; r < 4; ++r)
        reds[w * 32 + i * 16 + g * 4 + r] = sm[i][r];
  }
  __syncthreads();
#pragma unroll
  for (int i = 0; i < 2; ++i)
#pragma unroll
    for (int r = 0; r < 4; ++r) {
      int row = i * 16 + g * 4 + r;
      float s = reds[row] + reds[32 + row] + reds[64 + row] + reds[96 + row];
      sm[i][r] = 1.f / s;
    }

#pragma unroll
  for (int i = 0; i < 2; ++i)
#pragma unroll
    for (int j = 0; j < 8; ++j) {
      int col = w * 128 + j * 16 + lr;
#pragma unroll
      for (int r = 0; r < 4; ++r) {
        int row = i * 16 + g * 4 + r;
        float pn = accs[i][j][r] * sm[i][r];
        Ps[row * 520 + col] = f2b(pn);
        if (h == 0)
          attn_out[((size_t)(b * 512 + l0 + row)) * 512 + col] = pn;
      }
    }
  __syncthreads();

  f32x4 acco[2][4] = {};
  const unsigned short* vbase = vT + ((size_t)(b * 4 + h)) * 256 * 512;
#pragma unroll
  for (int ks = 0; ks < 16; ++ks) {
    int kj0 = ks * 32;
    bf16x8 a0 = *(const bf16x8*)&Ps[lr * 520 + kj0 + lk8];
    bf16x8 a1 = *(const bf16x8*)&Ps[(16 + lr) * 520 + kj0 + lk8];
#pragma unroll
    for (int j = 0; j < 4; ++j) {
      int d = w * 64 + j * 16 + lr;
      bf16x8 bb = *(const bf16x8*)&vbase[(size_t)d * 512 + kj0 + lk8];
      acco[0][j] = mfma16(a0, bb, acco[0][j]);
      acco[1][j] = mfma16(a1, bb, acco[1][j]);
    }
  }
#pragma unroll
  for (int i = 0; i < 2; ++i)
#pragma unroll
    for (int j = 0; j < 4; ++j) {
      int col = w * 64 + j * 16 + lr;
#pragma unroll
      for (int r = 0; r < 4; ++r) {
        int row = i * 16 + g * 4 + r;
        ctx[((size_t)(b * 512 + l0 + row)) * 1024 + h * 256 + col] = f2b(acco[i][j][r]);
      }
    }
}

// ---------------- LN + masked mean over L ----------------
__global__ __launch_bounds__(256)
void ln_mean(const unsigned short* __restrict__ sa, const float* __restrict__ g,
             const float* __restrict__ bt, const float* __restrict__ mask,
             float* __restrict__ poi_sum)
{
  const int b = blockIdx.y, ch = blockIdx.x;
  const int t = threadIdx.x, w = t >> 6, l = t & 63;
  float gg[16], bb[16];
#pragma unroll
  for (int j = 0; j < 16; ++j) { gg[j] = g[l * 16 + j]; bb[j] = bt[l * 16 + j]; }
  float accv[16];
#pragma unroll
  for (int j = 0; j < 16; ++j) accv[j] = 0.f;
  for (int rr = 0; rr < 16; ++rr) {
    int row = ch * 64 + w * 16 + rr;
    const unsigned short* rp = sa + ((size_t)(b * 512 + row)) * 1024 + l * 16;
    float x[16];
    sh8 v0 = *(const sh8*)rp;
    sh8 v1 = *(const sh8*)(rp + 8);
#pragma unroll
    for (int j = 0; j < 8; ++j) {
      x[j] = b2f((unsigned short)v0[j]);
      x[8 + j] = b2f((unsigned short)v1[j]);
    }
    float s = 0.f, s2 = 0.f;
#pragma unroll
    for (int j = 0; j < 16; ++j) { s += x[j]; s2 += x[j] * x[j]; }
#pragma unroll
    for (int off = 1; off < 64; off <<= 1) {
      s += __shfl_xor(s, off, 64);
      s2 += __shfl_xor(s2, off, 64);
    }
    float mean = s * (1.f / 1024.f);
    float var = s2 * (1.f / 1024.f) - mean * mean;
    float rinv = rsqrtf(var + 1e-5f);
    float mk = mask[b * 512 + row];
#pragma unroll
    for (int j = 0; j < 16; ++j) accv[j] += ((x[j] - mean) * rinv * gg[j] + bb[j]) * mk;
  }
#pragma unroll
  for (int j = 0; j < 16; ++j) atomicAdd(&poi_sum[b * 1024 + l * 16 + j], accv[j]);
}

__global__ void finalize_poi(const float* __restrict__ ps, float* __restrict__ poi) {
  int i = blockIdx.x * 256 + threadIdx.x;
  if (i < 32 * 1024) poi[i] = ps[i] * (1.f / 512.f);
}

__global__ __launch_bounds__(256)
void gemv32(const float* __restrict__ in, const float* __restrict__ W, float* __restrict__ out)
{
  const int b = blockIdx.y;
  const int n = blockIdx.x * 256 + threadIdx.x;
  const float* ib = in + b * 1024;
  float acc = 0.f;
  for (int d = 0; d < 1024; d += 4) {
    acc += ib[d]     * W[(size_t)d * 1024 + n]
         + ib[d + 1] * W[(size_t)(d + 1) * 1024 + n]
         + ib[d + 2] * W[(size_t)(d + 2) * 1024 + n]
         + ib[d + 3] * W[(size_t)(d + 3) * 1024 + n];
  }
  out[b * 1024 + n] = acc;
}

__global__ __launch_bounds__(256)
void softmax_his(float* __restrict__ sc, const float* __restrict__ mask)
{
  __shared__ float red[4];
  const int b = blockIdx.x, t = threadIdx.x, w = t >> 6, l = t & 63;
  float v[8];
  float mx = -3.0e38f;
#pragma unroll
  for (int i = 0; i < 8; ++i) {
    int kk = t + i * 256;
    float s = (mask[b * 2048 + kk] == 0.f) ? NEGV : sc[b * 2048 + kk];
    v[i] = s;
    mx = fmaxf(mx, s);
  }
#pragma unroll
  for (int off = 1; off < 64; off <<= 1) mx = fmaxf(mx, __shfl_xor(mx, off, 64));
  if (l == 0) red[w] = mx;
  __syncthreads();
  mx = fmaxf(fmaxf(red[0], red[1]), fmaxf(red[2], red[3]));
  float sum = 0.f;
#pragma unroll
  for (int i = 0; i < 8; ++i) { v[i] = __expf(v[i] - mx); sum += v[i]; }
#pragma unroll
  for (int off = 1; off < 64; off <<= 1) sum += __shfl_xor(sum, off, 64);
  __syncthreads();
  if (l == 0) red[w] = sum;
  __syncthreads();
  sum = red[0] + red[1] + red[2] + red[3];
  float inv = 1.f / sum;
#pragma unroll
  for (int i = 0; i < 8; ++i) sc[b * 2048 + t + i * 256] = v[i] * inv;
}

__global__ __launch_bounds__(256)
void hw_kernel(const float* __restrict__ aw, const unsigned short* __restrict__ his,
               float* __restrict__ hw)
{
  const int b = blockIdx.y, kc = blockIdx.x, t = threadIdx.x;
  const int cb = t * 4;
  float a0 = 0.f, a1 = 0.f, a2 = 0.f, a3 = 0.f;
  for (int kk = 0; kk < 256; ++kk) {
    int k = kc * 256 + kk;
    float wg = aw[b * 2048 + k];
    sh4 vv = *(const sh4*)&his[((size_t)(b * 2048 + k)) * 1024 + cb];
    a0 += wg * b2f((unsigned short)vv[0]);
    a1 += wg * b2f((unsigned short)vv[1]);
    a2 += wg * b2f((unsigned short)vv[2]);
    a3 += wg * b2f((unsigned short)vv[3]);
  }
  atomicAdd(&hw[b * 1024 + cb + 0], a0);
  atomicAdd(&hw[b * 1024 + cb + 1], a1);
  atomicAdd(&hw[b * 1024 + cb + 2], a2);
  atomicAdd(&hw[b * 1024 + cb + 3], a3);
}

__global__ __launch_bounds__(256)
void final_kernel(const float* __restrict__ aa_out, const float* __restrict__ g,
                  const float* __restrict__ bt, const float* __restrict__ poi,
                  float* __restrict__ out)
{
  __shared__ float r1[4], r2[4];
  const int b = blockIdx.x, t = threadIdx.x, w = t >> 6, l = t & 63;
  float x[4];
#pragma unroll
  for (int j = 0; j < 4; ++j) x[j] = aa_out[b * 1024 + t * 4 + j];
  float s = 0.f, s2 = 0.f;
#pragma unroll
  for (int j = 0; j < 4; ++j) { s += x[j]; s2 += x[j] * x[j]; }
#pragma unroll
  for (int off = 1; off < 64; off <<= 1) {
    s += __shfl_xor(s, off, 64);
    s2 += __shfl_xor(s2, off, 64);
  }
  if (l == 0) { r1[w] = s; r2[w] = s2; }
  __syncthreads();
  s = r1[0] + r1[1] + r1[2] + r1[3];
  s2 = r2[0] + r2[1] + r2[2] + r2[3];
  float mean = s * (1.f / 1024.f);
  float var = s2 * (1.f / 1024.f) - mean * mean;
  float rinv = rsqrtf(var + 1e-5f);
#pragma unroll
  for (int j = 0; j < 4; ++j) {
    int c = t * 4 + j;
    float lnv = (x[j] - mean) * rinv * g[c] + bt[c];
    float pv = poi[b * 1024 + c];
    out[b * 2048 + c] = pv;
    out[b * 2048 + 1024 + c] = pv + lnv;
  }
}

// ---------------- host launch ----------------
extern "C" void kernel_launch(void* const* d_in, const int* in_sizes, int n_in,
                              void* d_out, int out_size, void* d_ws, size_t ws_size,
                              hipStream_t stream)
{
  const float* seq_emb  = (const float*)d_in[0];
  const float* seq_mask = (const float*)d_in[1];
  const float* his_emb  = (const float*)d_in[2];
  const float* his_mask = (const float*)d_in[3];
  const float* sa_wq = (const float*)d_in[4];
  const float* sa_bq = (const float*)d_in[5];
  const float* sa_wk = (const float*)d_in[6];
  const float* sa_bk = (const float*)d_in[7];
  const float* sa_wv = (const float*)d_in[8];
  const float* sa_bv = (const float*)d_in[9];
  const float* sa_wo = (const float*)d_in[10];
  const float* sa_bo = (const float*)d_in[11];
  const float* sn_g  = (const float*)d_in[12];
  const float* sn_b  = (const float*)d_in[13];
  const float* aa_wq = (const float*)d_in[14];
  const float* aa_wk = (const float*)d_in[15];
  const float* aa_wv = (const float*)d_in[16];
  const float* aa_wo = (const float*)d_in[17];
  const float* aa_wa = (const float*)d_in[18];
  const float* ln_g  = (const float*)d_in[19];
  const float* ln_b  = (const float*)d_in[20];
  float* out = (float*)d_out;

  char* p = (char*)d_ws;
  size_t off = 0;
  auto alloc = [&](size_t bytes) -> void* {
    void* r = p + off;
    off += (bytes + 255) & ~(size_t)255;
    return r;
  };
  unsigned short* seqb = (unsigned short*)alloc((size_t)16384 * 1024 * 2);
  unsigned short* hisb = (unsigned short*)alloc((size_t)65536 * 1024 * 2);
  unsigned short* wcat = (unsigned short*)alloc((size_t)3072 * 1024 * 2);
  unsigned short* woT  = (unsigned short*)alloc((size_t)1024 * 1024 * 2);
  unsigned short* awkT = (unsigned short*)alloc((size_t)1024 * 1024 * 2);
  unsigned short* qb   = (unsigned short*)alloc((size_t)16384 * 1024 * 2);
  unsigned short* kb   = (unsigned short*)alloc((size_t)16384 * 1024 * 2);
  unsigned short* vTb  = (unsigned short*)alloc((size_t)16384 * 1024 * 2);
  unsigned short* ctxb = (unsigned short*)alloc((size_t)16384 * 1024 * 2);
  unsigned short* saob = (unsigned short*)alloc((size_t)16384 * 1024 * 2);
  float* poi_sum = (float*)alloc((size_t)32 * 1024 * 4);
  float* poi     = (float*)alloc((size_t)32 * 1024 * 4);
  float* aqb     = (float*)alloc((size_t)32 * 1024 * 4);
  float* ascore  = (float*)alloc((size_t)32 * 2048 * 4);
  float* hwb     = (float*)alloc((size_t)32 * 1024 * 4);
  float* actx    = (float*)alloc((size_t)32 * 1024 * 4);
  float* aaout   = (float*)alloc((size_t)32 * 1024 * 4);
  if (off > ws_size) return;

  hipMemsetAsync(poi_sum, 0, (size_t)32 * 1024 * 4, stream);
  hipMemsetAsync(ascore, 0, (size_t)32 * 2048 * 4, stream);
  hipMemsetAsync(hwb, 0, (size_t)32 * 1024 * 4, stream);

  cvt_bf16<<<2048, 256, 0, stream>>>(seq_emb, seqb, 16384 * 1024 / 4);
  cvt_bf16<<<2048, 256, 0, stream>>>(his_emb, hisb, 65536 * 1024 / 4);
  dim3 tg(16, 16);
  tcvt<<<tg, 256, 0, stream>>>(sa_wq, wcat);
  tcvt<<<tg, 256, 0, stream>>>(sa_wk, wcat + (size_t)1024 * 1024);
  tcvt<<<tg, 256, 0, stream>>>(sa_wv, wcat + (size_t)2048 * 1024);
  tcvt<<<tg, 256, 0, stream>>>(sa_wo, woT);
  tcvt<<<tg, 256, 0, stream>>>(aa_wk, awkT);

  // fused QKV: M=16384, N=3072 -> 64 x 12 = 768 blocks
  gemm256<1><<<768, 512, 0, stream>>>(seqb, wcat, 12, sa_bq, sa_bk, sa_bv,
                                      qb, kb, vTb, nullptr, nullptr, nullptr);

  attn_kernel<<<2048, 256, 0, stream>>>(qb, kb, vTb, seq_mask, ctxb, out + 65536);

  // sa_out: M=16384, N=1024 -> 64 x 4 = 256 blocks
  gemm256<0><<<256, 512, 0, stream>>>(ctxb, woT, 4, sa_bo, nullptr, nullptr,
                                      saob, nullptr, nullptr, nullptr, nullptr, nullptr);
  ln_mean<<<dim3(8, 32), 256, 0, stream>>>(saob, sn_g, sn_b, seq_mask, poi_sum);
  finalize_poi<<<128, 256, 0, stream>>>(poi_sum, poi);
  gemv32<<<dim3(4, 32), 256, 0, stream>>>(poi, aa_wq, aqb);

  // his scores: M=65536, N=1024 -> 256 x 4 = 1024 blocks
  gemm256<2><<<1024, 512, 0, stream>>>(hisb, awkT, 4, nullptr, nullptr, nullptr,
                                       nullptr, nullptr, nullptr, aqb, aa_wa, ascore);
  softmax_his<<<32, 256, 0, stream>>>(ascore, his_mask);
  hw_kernel<<<dim3(8, 32), 256, 0, stream>>>(ascore, hisb, hwb);
  gemv32<<<dim3(4, 32), 256, 0, stream>>>(hwb, aa_wv, actx);
  gemv32<<<dim3(4, 32), 256, 0, stream>>>(actx, aa_wo, aaout);
  final_kernel<<<32, 256, 0, stream>>>(aaout, ln_g, ln_b, poi, out);
}

// Round 4
// 795.563 us; speedup vs baseline: 1.2226x; 1.0339x over previous
//
#include <hip/hip_runtime.h>

#define NEGV (-1000000000.0f)

typedef __attribute__((ext_vector_type(8))) short sh8;
typedef __attribute__((ext_vector_type(4))) short sh4;
typedef __attribute__((ext_vector_type(8))) __bf16 bf16x8;
typedef __attribute__((ext_vector_type(4))) float f32x4;

__device__ __forceinline__ float b2f(unsigned short u) {
  unsigned v = ((unsigned)u) << 16;
  return __builtin_bit_cast(float, v);
}
__device__ __forceinline__ unsigned short f2b(float f) {
  unsigned x = __builtin_bit_cast(unsigned, f);
  unsigned r = (x + 0x7fffu + ((x >> 16) & 1u)) >> 16;
  return (unsigned short)r;
}
__device__ __forceinline__ void g2l16(const void* g, void* l) {
  __builtin_amdgcn_global_load_lds((const __attribute__((address_space(1))) unsigned int*)g,
                                   (__attribute__((address_space(3))) unsigned int*)l, 16, 0, 0);
}
__device__ __forceinline__ f32x4 mfma16(bf16x8 a, bf16x8 b, f32x4 c) {
  return __builtin_amdgcn_mfma_f32_16x16x32_bf16(a, b, c, 0, 0, 0);
}
__device__ __forceinline__ float fast_tanh(float x) {
  x = fminf(fmaxf(x, -15.f), 15.f);
  float e = __expf(2.f * x);
  return (e - 1.f) / (e + 1.f);
}

// ---------------- conversion kernels ----------------
__global__ void cvt_bf16(const float* __restrict__ src, unsigned short* __restrict__ dst, int n4) {
  int i = blockIdx.x * blockDim.x + threadIdx.x;
  int stride = gridDim.x * blockDim.x;
  for (; i < n4; i += stride) {
    float4 v = ((const float4*)src)[i];
    sh4 o;
    o[0] = (short)f2b(v.x); o[1] = (short)f2b(v.y);
    o[2] = (short)f2b(v.z); o[3] = (short)f2b(v.w);
    ((sh4*)dst)[i] = o;
  }
}

// dst[n][k] = bf16(src[k][n]) for 1024x1024
__global__ void tcvt(const float* __restrict__ src, unsigned short* __restrict__ dst) {
  __shared__ float tile[64][65];
  int bx = blockIdx.x, by = blockIdx.y;
  int tx = threadIdx.x & 63, ty = threadIdx.x >> 6;
#pragma unroll
  for (int i = 0; i < 16; ++i) {
    int r = i * 4 + ty;
    tile[r][tx] = src[(size_t)(by * 64 + r) * 1024 + bx * 64 + tx];
  }
  __syncthreads();
#pragma unroll
  for (int i = 0; i < 16; ++i) {
    int r = i * 4 + ty;
    dst[(size_t)(bx * 64 + r) * 1024 + by * 64 + tx] = f2b(tile[tx][r]);
  }
}

// ---------------- 256x256 bf16 MFMA GEMM, K=1024, ring-4 LDS, overlapped ----------------
// A: M x 1024 bf16 row-major. Bt: N x 1024 bf16 (n-major).
// 512 threads = 8 waves (2 wm x 4 wn); wave tile 128x64; acc[8][4] f32x4.
// BK=32; LDS ring of 4 x 32KB. Prefetch distance 2; ONE barrier + ONE counted
// vmcnt(4) per K-tile; ds_reads for tile kt+1 pre-issued after kt's barrier so
// LDS traffic overlaps MFMA (compiler emits counted lgkmcnt).
// Bank swizzle: 16B chunk index XORed with (row>>1)&3 on BOTH the staging
// global source and the ds_read address (LDS dest stays linear for g2l).
// EPI 0: row-major + bias. EPI 1: fused QKV. EPI 2: tanh-dot-atomic his-score.
template<int EPI>
__global__ __launch_bounds__(512, 1)
void gemm256(const unsigned short* __restrict__ A, const unsigned short* __restrict__ Bt,
             int nbx,
             const float* __restrict__ b0, const float* __restrict__ b1,
             const float* __restrict__ b2,
             unsigned short* __restrict__ O0, unsigned short* __restrict__ O1,
             unsigned short* __restrict__ O2,
             const float* __restrict__ aq, const float* __restrict__ wa,
             float* __restrict__ sc)
{
  __shared__ char lds[131072];
  const int tid = threadIdx.x;
  const int w = tid >> 6, l = tid & 63;
  const int wm = w >> 2, wn = w & 3;
  const int lr = l & 15, g = l >> 4;
  const int swz = (lr >> 1) & 3;

  // bijective XCD swizzle (gridDim.x % 8 == 0 for all our shapes)
  const int wg = blockIdx.x;
  const int cpx = gridDim.x >> 3;
  const int wgid = (wg & 7) * cpx + (wg >> 3);
  const int bx = wgid % nbx, by = wgid / nbx;
  const size_t m0 = (size_t)by * 256;
  const int n0 = bx * 256;

  f32x4 acc[8][4] = {};

  // staging: thread covers row tid>>2 of a 128-row half; source chunk pre-swizzled
  const int srow = tid >> 2;
  const int sk = (((tid & 3) ^ ((tid >> 3) & 3)) * 8);
  const unsigned short* gA = A + (m0 + srow) * 1024 + sk;
  const unsigned short* gB = Bt + ((size_t)n0 + srow) * 1024 + sk;
  char* const sbase = lds + w * 1024;  // wave-uniform; HW adds lane*16

  // compute-side swizzled LDS byte offsets (within a 32KB buffer)
  const int aoff = (wm * 128 + lr) * 64 + ((g ^ swz) * 16);          // + i*1024 per frag
  const int boff = 16384 + (wn * 64 + lr) * 64 + ((g ^ swz) * 16);   // + j*1024 per frag

  bf16x8 af[4], bf[4], af2[4];

  auto stageA = [&](int kt) {
    const unsigned short* a = gA + kt * 32;
    char* base = sbase + ((kt & 3) << 15);
    g2l16(a, base);
    g2l16(a + 128 * 1024, base + 8192);
  };
  auto stageB = [&](int kt) {
    const unsigned short* b = gB + kt * 32;
    char* base = sbase + ((kt & 3) << 15);
    g2l16(b, base + 16384);
    g2l16(b + 128 * 1024, base + 24576);
  };
  auto loadFirst = [&](int kt) {
    const char* pb = lds + ((kt & 3) << 15);
#pragma unroll
    for (int j = 0; j < 4; ++j) bf[j] = *(const bf16x8*)(pb + boff + j * 1024);
#pragma unroll
    for (int i = 0; i < 4; ++i) af[i] = *(const bf16x8*)(pb + aoff + i * 1024);
  };

  // ---- prologue ----
  stageA(0); stageB(0); stageA(1); stageB(1);
  asm volatile("s_waitcnt vmcnt(4)" ::: "memory");  // tile 0 resident, tile 1 in flight
  __builtin_amdgcn_s_barrier();
  __builtin_amdgcn_sched_barrier(0);
  loadFirst(0);
  __builtin_amdgcn_sched_barrier(0);

#pragma unroll 1
  for (int kt = 0; kt < 32; ++kt) {
    const char* pb = lds + ((kt & 3) << 15);
    if (kt < 30) stageA(kt + 2);
#pragma unroll
    for (int i = 0; i < 4; ++i) af2[i] = *(const bf16x8*)(pb + aoff + (4 + i) * 1024);
    if (kt < 30) stageB(kt + 2);
    __builtin_amdgcn_sched_barrier(0);
    // block 0: rows 0-63 (compiler inserts counted lgkmcnt for af/bf only)
    __builtin_amdgcn_s_setprio(1);
#pragma unroll
    for (int i = 0; i < 4; ++i)
#pragma unroll
      for (int j = 0; j < 4; ++j)
        acc[i][j] = mfma16(af[i], bf[j], acc[i][j]);
    __builtin_amdgcn_s_setprio(0);
    // block 1: rows 64-127
    __builtin_amdgcn_s_setprio(1);
#pragma unroll
    for (int i = 0; i < 4; ++i)
#pragma unroll
      for (int j = 0; j < 4; ++j)
        acc[4 + i][j] = mfma16(af2[i], bf[j], acc[4 + i][j]);
    __builtin_amdgcn_s_setprio(0);
    if (kt < 30) {
      asm volatile("s_waitcnt vmcnt(4)" ::: "memory");   // kt+1 resident, kt+2 in flight
    } else if (kt == 30) {
      asm volatile("s_waitcnt vmcnt(0)" ::: "memory");
    }
    __builtin_amdgcn_s_barrier();
    __builtin_amdgcn_sched_barrier(0);
    if (kt < 31) loadFirst(kt + 1);     // pre-issue next tile's 8 reads
    __builtin_amdgcn_sched_barrier(0);
  }

  // ======== epilogue ========
  if (EPI == 0) {
#pragma unroll
    for (int j = 0; j < 4; ++j) {
      int col = n0 + wn * 64 + j * 16 + lr;
      float bv = b0[col];
#pragma unroll
      for (int i = 0; i < 8; ++i) {
        size_t rowb = m0 + wm * 128 + i * 16 + g * 4;
#pragma unroll
        for (int r = 0; r < 4; ++r)
          O0[(rowb + r) * 1024 + col] = f2b(acc[i][j][r] + bv);
      }
    }
  } else if (EPI == 1) {
#pragma unroll
    for (int j = 0; j < 4; ++j) {
      int col3 = n0 + wn * 64 + j * 16 + lr;
      int part = col3 >> 10, c = col3 & 1023;
      float bv = (part == 0) ? b0[c] : (part == 1) ? b1[c] : b2[c];
      if (part < 2) {
        unsigned short* O = part == 0 ? O0 : O1;
#pragma unroll
        for (int i = 0; i < 8; ++i) {
          size_t rowb = m0 + wm * 128 + i * 16 + g * 4;
#pragma unroll
          for (int r = 0; r < 4; ++r)
            O[(rowb + r) * 1024 + c] = f2b(acc[i][j][r] + bv);
        }
      } else {  // v: transposed layout vT[(b*4+h)*256 + d][512] = v[b, l, h, d]
        int h = c >> 8, d = c & 255;
#pragma unroll
        for (int i = 0; i < 8; ++i) {
          size_t row = m0 + wm * 128 + i * 16 + g * 4;
          int bb = (int)(row >> 9), ll = (int)(row & 511);
          size_t base = ((size_t)(bb * 4 + h) * 256 + d) * 512 + ll;
#pragma unroll
          for (int r = 0; r < 4; ++r)
            O2[base + r] = f2b(acc[i][j][r] + bv);
        }
      }
    }
  } else {
    const int bb = (int)(m0 >> 11);
#pragma unroll
    for (int i = 0; i < 8; ++i) {
      float rp[4] = {0.f, 0.f, 0.f, 0.f};
#pragma unroll
      for (int j = 0; j < 4; ++j) {
        int col = n0 + wn * 64 + j * 16 + lr;
        float wav = wa[col];
        float aqv = aq[bb * 1024 + col];
#pragma unroll
        for (int r = 0; r < 4; ++r)
          rp[r] += wav * fast_tanh(acc[i][j][r] + aqv);
      }
#pragma unroll
      for (int off = 1; off < 16; off <<= 1)
#pragma unroll
        for (int r = 0; r < 4; ++r)
          rp[r] += __shfl_xor(rp[r], off, 64);
      if (lr == 0) {
        size_t rowb = m0 + wm * 128 + i * 16 + g * 4;
#pragma unroll
        for (int r = 0; r < 4; ++r)
          atomicAdd(&sc[rowb + r], rp[r]);
      }
    }
  }
}

// ---------------- fused attention (register softmax, 34.3KB LDS) ----------------
__global__ __launch_bounds__(256, 4)
void attn_kernel(const unsigned short* __restrict__ q, const unsigned short* __restrict__ k,
                 const unsigned short* __restrict__ vT, const float* __restrict__ seq_mask,
                 unsigned short* __restrict__ ctx, float* __restrict__ attn_out)
{
  __shared__ char smem[34304];
  unsigned short* Qs = (unsigned short*)smem;
  unsigned short* Ps = (unsigned short*)smem;
  float* redm = (float*)(smem + 33280);
  float* reds = (float*)(smem + 33792);
  const int t = threadIdx.x, w = t >> 6, l = t & 63;
  const int lr = l & 15, g = l >> 4, lk8 = g * 8;
  const int wg = blockIdx.x;
  const int wgid = (wg & 7) * 256 + (wg >> 3);
  const int qt = wgid & 15, bh = wgid >> 4;
  const int h = bh & 3, b = bh >> 2;
  const int l0 = qt * 32;

  for (int idx = t; idx < 32 * 32; idx += 256) {
    int r = idx >> 5, ch = (idx & 31) * 8;
    *(sh8*)&Qs[r * 264 + ch] =
        *(const sh8*)&q[((size_t)(b * 512 + l0 + r)) * 1024 + h * 256 + ch];
  }
  __syncthreads();

  f32x4 accs[2][8] = {};
  const unsigned short* kbase = k + ((size_t)b * 512) * 1024 + h * 256;
#pragma unroll
  for (int ds = 0; ds < 8; ++ds) {
    int d0 = ds * 32;
    bf16x8 a0 = *(const bf16x8*)&Qs[lr * 264 + d0 + lk8];
    bf16x8 a1 = *(const bf16x8*)&Qs[(16 + lr) * 264 + d0 + lk8];
#pragma unroll
    for (int j = 0; j < 8; ++j) {
      int kj = w * 128 + j * 16 + lr;
      bf16x8 bb = *(const bf16x8*)&kbase[(size_t)kj * 1024 + d0 + lk8];
      accs[0][j] = mfma16(a0, bb, accs[0][j]);
      accs[1][j] = mfma16(a1, bb, accs[1][j]);
    }
  }

#pragma unroll
  for (int j = 0; j < 8; ++j) {
    int col = w * 128 + j * 16 + lr;
    float mv = seq_mask[b * 512 + col];
    bool msk = (mv == 0.f);
#pragma unroll
    for (int i = 0; i < 2; ++i)
#pragma unroll
      for (int r = 0; r < 4; ++r)
        accs[i][j][r] = msk ? NEGV : accs[i][j][r] * 0.0625f;
  }

  float mx[2][4], sm[2][4];
#pragma unroll
  for (int i = 0; i < 2; ++i)
#pragma unroll
    for (int r = 0; r < 4; ++r) {
      float m = accs[i][0][r];
#pragma unroll
      for (int j = 1; j < 8; ++j) m = fmaxf(m, accs[i][j][r]);
      mx[i][r] = m;
    }
#pragma unroll
  for (int off = 1; off < 16; off <<= 1)
#pragma unroll
    for (int i = 0; i < 2; ++i)
#pragma unroll
      for (int r = 0; r < 4; ++r)
        mx[i][r] = fmaxf(mx[i][r], __shfl_xor(mx[i][r], off, 64));
  if (lr == 0) {
#pragma unroll
    for (int i = 0; i < 2; ++i)
#pragma unroll
      for (int r = 0; r < 4; ++r)
        redm[w * 32 + i * 16 + g * 4 + r] = mx[i][r];
  }
  __syncthreads();
#pragma unroll
  for (int i = 0; i < 2; ++i)
#pragma unroll
    for (int r = 0; r < 4; ++r) {
      int row = i * 16 + g * 4 + r;
      mx[i][r] = fmaxf(fmaxf(redm[row], redm[32 + row]),
                       fmaxf(redm[64 + row], redm[96 + row]));
      sm[i][r] = 0.f;
    }

#pragma unroll
  for (int i = 0; i < 2; ++i)
#pragma unroll
    for (int j = 0; j < 8; ++j)
#pragma unroll
      for (int r = 0; r < 4; ++r) {
        float p = __expf(accs[i][j][r] - mx[i][r]);
        accs[i][j][r] = p;
        sm[i][r] += p;
      }
#pragma unroll
  for (int off = 1; off < 16; off <<= 1)
#pragma unroll
    for (int i = 0; i < 2; ++i)
#pragma unroll
      for (int r = 0; r < 4; ++r)
        sm[i][r] += __shfl_xor(sm[i][r], off, 64);
  if (lr == 0) {
#pragma unroll
    for (int i = 0; i < 2; ++i)
#pragma unroll
      for (int r = 0; r < 4; ++r)
        reds[w * 32 + i * 16 + g * 4 + r] = sm[i][r];
  }
  __syncthreads();
#pragma unroll
  for (int i = 0; i < 2; ++i)
#pragma unroll
    for (int r = 0; r < 4; ++r) {
      int row = i * 16 + g * 4 + r;
      float s = reds[row] + reds[32 + row] + reds[64 + row] + reds[96 + row];
      sm[i][r] = 1.f / s;
    }

#pragma unroll
  for (int i = 0; i < 2; ++i)
#pragma unroll
    for (int j = 0; j < 8; ++j) {
      int col = w * 128 + j * 16 + lr;
#pragma unroll
      for (int r = 0; r < 4; ++r) {
        int row = i * 16 + g * 4 + r;
        float pn = accs[i][j][r] * sm[i][r];
        Ps[row * 520 + col] = f2b(pn);
        if (h == 0)
          attn_out[((size_t)(b * 512 + l0 + row)) * 512 + col] = pn;
      }
    }
  __syncthreads();

  f32x4 acco[2][4] = {};
  const unsigned short* vbase = vT + ((size_t)(b * 4 + h)) * 256 * 512;
#pragma unroll
  for (int ks = 0; ks < 16; ++ks) {
    int kj0 = ks * 32;
    bf16x8 a0 = *(const bf16x8*)&Ps[lr * 520 + kj0 + lk8];
    bf16x8 a1 = *(const bf16x8*)&Ps[(16 + lr) * 520 + kj0 + lk8];
#pragma unroll
    for (int j = 0; j < 4; ++j) {
      int d = w * 64 + j * 16 + lr;
      bf16x8 bb = *(const bf16x8*)&vbase[(size_t)d * 512 + kj0 + lk8];
      acco[0][j] = mfma16(a0, bb, acco[0][j]);
      acco[1][j] = mfma16(a1, bb, acco[1][j]);
    }
  }
#pragma unroll
  for (int i = 0; i < 2; ++i)
#pragma unroll
    for (int j = 0; j < 4; ++j) {
      int col = w * 64 + j * 16 + lr;
#pragma unroll
      for (int r = 0; r < 4; ++r) {
        int row = i * 16 + g * 4 + r;
        ctx[((size_t)(b * 512 + l0 + row)) * 1024 + h * 256 + col] = f2b(acco[i][j][r]);
      }
    }
}

// ---------------- LN + masked mean over L ----------------
__global__ __launch_bounds__(256)
void ln_mean(const unsigned short* __restrict__ sa, const float* __restrict__ g,
             const float* __restrict__ bt, const float* __restrict__ mask,
             float* __restrict__ poi_sum)
{
  const int b = blockIdx.y, ch = blockIdx.x;
  const int t = threadIdx.x, w = t >> 6, l = t & 63;
  float gg[16], bb[16];
#pragma unroll
  for (int j = 0; j < 16; ++j) { gg[j] = g[l * 16 + j]; bb[j] = bt[l * 16 + j]; }
  float accv[16];
#pragma unroll
  for (int j = 0; j < 16; ++j) accv[j] = 0.f;
  for (int rr = 0; rr < 16; ++rr) {
    int row = ch * 64 + w * 16 + rr;
    const unsigned short* rp = sa + ((size_t)(b * 512 + row)) * 1024 + l * 16;
    float x[16];
    sh8 v0 = *(const sh8*)rp;
    sh8 v1 = *(const sh8*)(rp + 8);
#pragma unroll
    for (int j = 0; j < 8; ++j) {
      x[j] = b2f((unsigned short)v0[j]);
      x[8 + j] = b2f((unsigned short)v1[j]);
    }
    float s = 0.f, s2 = 0.f;
#pragma unroll
    for (int j = 0; j < 16; ++j) { s += x[j]; s2 += x[j] * x[j]; }
#pragma unroll
    for (int off = 1; off < 64; off <<= 1) {
      s += __shfl_xor(s, off, 64);
      s2 += __shfl_xor(s2, off, 64);
    }
    float mean = s * (1.f / 1024.f);
    float var = s2 * (1.f / 1024.f) - mean * mean;
    float rinv = rsqrtf(var + 1e-5f);
    float mk = mask[b * 512 + row];
#pragma unroll
    for (int j = 0; j < 16; ++j) accv[j] += ((x[j] - mean) * rinv * gg[j] + bb[j]) * mk;
  }
#pragma unroll
  for (int j = 0; j < 16; ++j) atomicAdd(&poi_sum[b * 1024 + l * 16 + j], accv[j]);
}

__global__ void finalize_poi(const float* __restrict__ ps, float* __restrict__ poi) {
  int i = blockIdx.x * 256 + threadIdx.x;
  if (i < 32 * 1024) poi[i] = ps[i] * (1.f / 512.f);
}

__global__ __launch_bounds__(256)
void gemv32(const float* __restrict__ in, const float* __restrict__ W, float* __restrict__ out)
{
  const int b = blockIdx.y;
  const int n = blockIdx.x * 256 + threadIdx.x;
  const float* ib = in + b * 1024;
  float acc = 0.f;
  for (int d = 0; d < 1024; d += 4) {
    acc += ib[d]     * W[(size_t)d * 1024 + n]
         + ib[d + 1] * W[(size_t)(d + 1) * 1024 + n]
         + ib[d + 2] * W[(size_t)(d + 2) * 1024 + n]
         + ib[d + 3] * W[(size_t)(d + 3) * 1024 + n];
  }
  out[b * 1024 + n] = acc;
}

__global__ __launch_bounds__(256)
void softmax_his(float* __restrict__ sc, const float* __restrict__ mask)
{
  __shared__ float red[4];
  const int b = blockIdx.x, t = threadIdx.x, w = t >> 6, l = t & 63;
  float v[8];
  float mx = -3.0e38f;
#pragma unroll
  for (int i = 0; i < 8; ++i) {
    int kk = t + i * 256;
    float s = (mask[b * 2048 + kk] == 0.f) ? NEGV : sc[b * 2048 + kk];
    v[i] = s;
    mx = fmaxf(mx, s);
  }
#pragma unroll
  for (int off = 1; off < 64; off <<= 1) mx = fmaxf(mx, __shfl_xor(mx, off, 64));
  if (l == 0) red[w] = mx;
  __syncthreads();
  mx = fmaxf(fmaxf(red[0], red[1]), fmaxf(red[2], red[3]));
  float sum = 0.f;
#pragma unroll
  for (int i = 0; i < 8; ++i) { v[i] = __expf(v[i] - mx); sum += v[i]; }
#pragma unroll
  for (int off = 1; off < 64; off <<= 1) sum += __shfl_xor(sum, off, 64);
  __syncthreads();
  if (l == 0) red[w] = sum;
  __syncthreads();
  sum = red[0] + red[1] + red[2] + red[3];
  float inv = 1.f / sum;
#pragma unroll
  for (int i = 0; i < 8; ++i) sc[b * 2048 + t + i * 256] = v[i] * inv;
}

__global__ __launch_bounds__(256)
void hw_kernel(const float* __restrict__ aw, const unsigned short* __restrict__ his,
               float* __restrict__ hw)
{
  const int b = blockIdx.y, kc = blockIdx.x, t = threadIdx.x;
  const int cb = t * 4;
  float a0 = 0.f, a1 = 0.f, a2 = 0.f, a3 = 0.f;
  for (int kk = 0; kk < 256; ++kk) {
    int k = kc * 256 + kk;
    float wg = aw[b * 2048 + k];
    sh4 vv = *(const sh4*)&his[((size_t)(b * 2048 + k)) * 1024 + cb];
    a0 += wg * b2f((unsigned short)vv[0]);
    a1 += wg * b2f((unsigned short)vv[1]);
    a2 += wg * b2f((unsigned short)vv[2]);
    a3 += wg * b2f((unsigned short)vv[3]);
  }
  atomicAdd(&hw[b * 1024 + cb + 0], a0);
  atomicAdd(&hw[b * 1024 + cb + 1], a1);
  atomicAdd(&hw[b * 1024 + cb + 2], a2);
  atomicAdd(&hw[b * 1024 + cb + 3], a3);
}

__global__ __launch_bounds__(256)
void final_kernel(const float* __restrict__ aa_out, const float* __restrict__ g,
                  const float* __restrict__ bt, const float* __restrict__ poi,
                  float* __restrict__ out)
{
  __shared__ float r1[4], r2[4];
  const int b = blockIdx.x, t = threadIdx.x, w = t >> 6, l = t & 63;
  float x[4];
#pragma unroll
  for (int j = 0; j < 4; ++j) x[j] = aa_out[b * 1024 + t * 4 + j];
  float s = 0.f, s2 = 0.f;
#pragma unroll
  for (int j = 0; j < 4; ++j) { s += x[j]; s2 += x[j] * x[j]; }
#pragma unroll
  for (int off = 1; off < 64; off <<= 1) {
    s += __shfl_xor(s, off, 64);
    s2 += __shfl_xor(s2, off, 64);
  }
  if (l == 0) { r1[w] = s; r2[w] = s2; }
  __syncthreads();
  s = r1[0] + r1[1] + r1[2] + r1[3];
  s2 = r2[0] + r2[1] + r2[2] + r2[3];
  float mean = s * (1.f / 1024.f);
  float var = s2 * (1.f / 1024.f) - mean * mean;
  float rinv = rsqrtf(var + 1e-5f);
#pragma unroll
  for (int j = 0; j < 4; ++j) {
    int c = t * 4 + j;
    float lnv = (x[j] - mean) * rinv * g[c] + bt[c];
    float pv = poi[b * 1024 + c];
    out[b * 2048 + c] = pv;
    out[b * 2048 + 1024 + c] = pv + lnv;
  }
}

// ---------------- host launch ----------------
extern "C" void kernel_launch(void* const* d_in, const int* in_sizes, int n_in,
                              void* d_out, int out_size, void* d_ws, size_t ws_size,
                              hipStream_t stream)
{
  const float* seq_emb  = (const float*)d_in[0];
  const float* seq_mask = (const float*)d_in[1];
  const float* his_emb  = (const float*)d_in[2];
  const float* his_mask = (const float*)d_in[3];
  const float* sa_wq = (const float*)d_in[4];
  const float* sa_bq = (const float*)d_in[5];
  const float* sa_wk = (const float*)d_in[6];
  const float* sa_bk = (const float*)d_in[7];
  const float* sa_wv = (const float*)d_in[8];
  const float* sa_bv = (const float*)d_in[9];
  const float* sa_wo = (const float*)d_in[10];
  const float* sa_bo = (const float*)d_in[11];
  const float* sn_g  = (const float*)d_in[12];
  const float* sn_b  = (const float*)d_in[13];
  const float* aa_wq = (const float*)d_in[14];
  const float* aa_wk = (const float*)d_in[15];
  const float* aa_wv = (const float*)d_in[16];
  const float* aa_wo = (const float*)d_in[17];
  const float* aa_wa = (const float*)d_in[18];
  const float* ln_g  = (const float*)d_in[19];
  const float* ln_b  = (const float*)d_in[20];
  float* out = (float*)d_out;

  char* p = (char*)d_ws;
  size_t off = 0;
  auto alloc = [&](size_t bytes) -> void* {
    void* r = p + off;
    off += (bytes + 255) & ~(size_t)255;
    return r;
  };
  unsigned short* seqb = (unsigned short*)alloc((size_t)16384 * 1024 * 2);
  unsigned short* hisb = (unsigned short*)alloc((size_t)65536 * 1024 * 2);
  unsigned short* wcat = (unsigned short*)alloc((size_t)3072 * 1024 * 2);
  unsigned short* woT  = (unsigned short*)alloc((size_t)1024 * 1024 * 2);
  unsigned short* awkT = (unsigned short*)alloc((size_t)1024 * 1024 * 2);
  unsigned short* qb   = (unsigned short*)alloc((size_t)16384 * 1024 * 2);
  unsigned short* kb   = (unsigned short*)alloc((size_t)16384 * 1024 * 2);
  unsigned short* vTb  = (unsigned short*)alloc((size_t)16384 * 1024 * 2);
  unsigned short* ctxb = (unsigned short*)alloc((size_t)16384 * 1024 * 2);
  unsigned short* saob = (unsigned short*)alloc((size_t)16384 * 1024 * 2);
  float* poi_sum = (float*)alloc((size_t)32 * 1024 * 4);
  float* poi     = (float*)alloc((size_t)32 * 1024 * 4);
  float* aqb     = (float*)alloc((size_t)32 * 1024 * 4);
  float* ascore  = (float*)alloc((size_t)32 * 2048 * 4);
  float* hwb     = (float*)alloc((size_t)32 * 1024 * 4);
  float* actx    = (float*)alloc((size_t)32 * 1024 * 4);
  float* aaout   = (float*)alloc((size_t)32 * 1024 * 4);
  if (off > ws_size) return;

  hipMemsetAsync(poi_sum, 0, (size_t)32 * 1024 * 4, stream);
  hipMemsetAsync(ascore, 0, (size_t)32 * 2048 * 4, stream);
  hipMemsetAsync(hwb, 0, (size_t)32 * 1024 * 4, stream);

  cvt_bf16<<<2048, 256, 0, stream>>>(seq_emb, seqb, 16384 * 1024 / 4);
  cvt_bf16<<<2048, 256, 0, stream>>>(his_emb, hisb, 65536 * 1024 / 4);
  dim3 tg(16, 16);
  tcvt<<<tg, 256, 0, stream>>>(sa_wq, wcat);
  tcvt<<<tg, 256, 0, stream>>>(sa_wk, wcat + (size_t)1024 * 1024);
  tcvt<<<tg, 256, 0, stream>>>(sa_wv, wcat + (size_t)2048 * 1024);
  tcvt<<<tg, 256, 0, stream>>>(sa_wo, woT);
  tcvt<<<tg, 256, 0, stream>>>(aa_wk, awkT);

  // fused QKV: M=16384, N=3072 -> 64 x 12 = 768 blocks
  gemm256<1><<<768, 512, 0, stream>>>(seqb, wcat, 12, sa_bq, sa_bk, sa_bv,
                                      qb, kb, vTb, nullptr, nullptr, nullptr);

  attn_kernel<<<2048, 256, 0, stream>>>(qb, kb, vTb, seq_mask, ctxb, out + 65536);

  // sa_out: M=16384, N=1024 -> 64 x 4 = 256 blocks
  gemm256<0><<<256, 512, 0, stream>>>(ctxb, woT, 4, sa_bo, nullptr, nullptr,
                                      saob, nullptr, nullptr, nullptr, nullptr, nullptr);
  ln_mean<<<dim3(8, 32), 256, 0, stream>>>(saob, sn_g, sn_b, seq_mask, poi_sum);
  finalize_poi<<<128, 256, 0, stream>>>(poi_sum, poi);
  gemv32<<<dim3(4, 32), 256, 0, stream>>>(poi, aa_wq, aqb);

  // his scores: M=65536, N=1024 -> 256 x 4 = 1024 blocks
  gemm256<2><<<1024, 512, 0, stream>>>(hisb, awkT, 4, nullptr, nullptr, nullptr,
                                       nullptr, nullptr, nullptr, aqb, aa_wa, ascore);
  softmax_his<<<32, 256, 0, stream>>>(ascore, his_mask);
  hw_kernel<<<dim3(8, 32), 256, 0, stream>>>(ascore, hisb, hwb);
  gemv32<<<dim3(4, 32), 256, 0, stream>>>(hwb, aa_wv, actx);
  gemv32<<<dim3(4, 32), 256, 0, stream>>>(actx, aa_wo, aaout);
  final_kernel<<<32, 256, 0, stream>>>(aaout, ln_g, ln_b, poi, out);
}